// Round 2
// baseline (1009.349 us; speedup 1.0000x reference)
//
#include <hip/hip_runtime.h>

#define NNODE 16384
#define DD 32
#define INPC 256
#define UC 128
#define RC 8
#define EC 8

// ---------- prep: P = (q_w @ k_w^T) / U ----------
__global__ void k_qkt(const float* __restrict__ qw, const float* __restrict__ kw,
                      float* __restrict__ P) {
    int id = blockIdx.x * 256 + threadIdx.x;      // 64 blocks * 256 = 16384 = 128*128
    int i = id >> 7, j = id & 127;
    const float4* qr = (const float4*)(qw + i * UC);
    const float4* kr = (const float4*)(kw + j * UC);
    float acc = 0.f;
    #pragma unroll
    for (int lc = 0; lc < 32; ++lc) {
        float4 a = qr[lc], b = kr[lc];
        acc += a.x * b.x + a.y * b.y + a.z * b.z + a.w * b.w;
    }
    P[id] = acc * (1.0f / 128.0f);
}

// ---------- prep: M[r] = P @ rel_w[r]^T ; RV[r] = rel_w[r] @ v_w ----------
__global__ void k_mrv(const float* __restrict__ P, const float* __restrict__ relw,
                      const float* __restrict__ vw, float* __restrict__ Mmat,
                      float* __restrict__ RVmat) {
    int r = blockIdx.x, i0 = blockIdx.y * 16;
    const float* R = relw + r * UC * UC;
    int j = threadIdx.x & 127, h = threadIdx.x >> 7;

    float accM[8] = {0,0,0,0,0,0,0,0};
    for (int mc = 0; mc < 32; ++mc) {
        float4 rv = *(const float4*)&R[j * UC + mc * 4];
        #pragma unroll
        for (int ii = 0; ii < 8; ++ii) {
            float4 p = *(const float4*)&P[(i0 + h * 8 + ii) * UC + mc * 4];
            accM[ii] += p.x * rv.x + p.y * rv.y + p.z * rv.z + p.w * rv.w;
        }
    }
    #pragma unroll
    for (int ii = 0; ii < 8; ++ii)
        Mmat[(r * UC + (i0 + h * 8 + ii)) * UC + j] = accM[ii];

    float accV[8] = {0,0,0,0,0,0,0,0};
    for (int m = 0; m < UC; ++m) {
        float v = vw[m * UC + j];
        #pragma unroll
        for (int ii = 0; ii < 8; ++ii)
            accV[ii] += R[(i0 + h * 8 + ii) * UC + m] * v;
    }
    #pragma unroll
    for (int ii = 0; ii < 8; ++ii)
        RVmat[(r * UC + (i0 + h * 8 + ii)) * UC + j] = accV[ii];
}

// ---------- compaction by entity ----------
__global__ void k_count(const int* __restrict__ pe, int* __restrict__ cnt) {
    int n = blockIdx.x * 256 + threadIdx.x;
    atomicAdd(&cnt[pe[n]], 1);
}
__global__ void k_scan(const int* __restrict__ cnt, int* __restrict__ base) {
    if (threadIdx.x == 0) {
        int run = 0;
        for (int e = 0; e < EC; ++e) { base[e] = run; run += cnt[e]; }
    }
}
__global__ void k_scatter(const int* __restrict__ pe, const int* __restrict__ base,
                          int* __restrict__ cnt2, int* __restrict__ list) {
    int n = blockIdx.x * 256 + threadIdx.x;
    int e = pe[n];
    int pos = base[e] + atomicAdd(&cnt2[e], 1);
    list[pos] = n;
}

// ---------- center[n] = node_state[n] @ point_enc_w[pe[n]] ----------
__global__ void k_center(const float* __restrict__ ns, const float* __restrict__ pew,
                         const int* __restrict__ list, const int* __restrict__ cnt,
                         const int* __restrict__ base, float* __restrict__ center) {
    int e = blockIdx.y;
    int start = blockIdx.x * 32;
    int c = cnt[e];
    if (start >= c) return;
    int m = min(32, c - start);

    __shared__ float ns_s[32 * 256];   // 32 KB
    __shared__ int ids_s[32];
    if ((int)threadIdx.x < m) ids_s[threadIdx.x] = list[base[e] + start + threadIdx.x];
    __syncthreads();
    for (int idx = threadIdx.x; idx < m * 256; idx += 256)
        ns_s[idx] = ns[ids_s[idx >> 8] * INPC + (idx & 255)];
    __syncthreads();

    int j = threadIdx.x & 127, h = threadIdx.x >> 7;
    const float* W = pew + (size_t)e * INPC * UC;
    float acc[16];
    #pragma unroll
    for (int rr = 0; rr < 16; ++rr) acc[rr] = 0.f;

    for (int kc = 0; kc < 64; ++kc) {
        float w0 = W[(kc * 4 + 0) * UC + j];
        float w1 = W[(kc * 4 + 1) * UC + j];
        float w2 = W[(kc * 4 + 2) * UC + j];
        float w3 = W[(kc * 4 + 3) * UC + j];
        #pragma unroll
        for (int rr = 0; rr < 16; ++rr) {
            float4 nv = *(const float4*)&ns_s[(h * 16 + rr) * 256 + kc * 4];
            acc[rr] += nv.x * w0 + nv.y * w1 + nv.z * w2 + nv.w * w3;
        }
    }
    #pragma unroll
    for (int rr = 0; rr < 16; ++rr) {
        int row = h * 16 + rr;
        if (row < m) center[ids_s[row] * UC + j] = acc[rr];
    }
}

// ---------- fused: qr = center @ M[r] (LDS, col-swizzled), scores, softmax ----------
// LDS layout: qr_s[row*128 + ((col + r*4)&127)], row = tn*8 + r.
// Swizzle puts the 8 relation rows of a node in 8 distinct bank groups so
// phase-B's per-lane (rd-indexed) ds_read_b128 is conflict-free.
__global__ void k_scores(const float* __restrict__ center, const float* __restrict__ Mmat,
                         const int* __restrict__ adj, const int* __restrict__ rel,
                         float* __restrict__ attn) {
    __shared__ float qr_s[16 * 8 * 128];   // 64 KB
    int n0 = blockIdx.x * 16;
    int j = threadIdx.x & 127, h = threadIdx.x >> 7;

    float acc[8][8];   // [r][nn]
    #pragma unroll
    for (int r = 0; r < 8; ++r)
        #pragma unroll
        for (int nn = 0; nn < 8; ++nn) acc[r][nn] = 0.f;

    for (int kc = 0; kc < 32; ++kc) {
        float4 cv[8];
        #pragma unroll
        for (int nn = 0; nn < 8; ++nn)
            cv[nn] = *(const float4*)&center[(n0 + h * 8 + nn) * UC + kc * 4]; // wave-uniform
        #pragma unroll
        for (int kk = 0; kk < 4; ++kk) {
            #pragma unroll
            for (int r = 0; r < 8; ++r) {
                float w = Mmat[(r * UC + kc * 4 + kk) * UC + j];  // coalesced, L2-hot
                #pragma unroll
                for (int nn = 0; nn < 8; ++nn)
                    acc[r][nn] += ((const float*)&cv[nn])[kk] * w;
            }
        }
    }
    #pragma unroll
    for (int r = 0; r < 8; ++r)
        #pragma unroll
        for (int nn = 0; nn < 8; ++nn)
            qr_s[((h * 8 + nn) * 8 + r) * 128 + ((j + r * 4) & 127)] = acc[r][nn];
    __syncthreads();

    // phase B: edge-parallel. lane = half*32 + d; each lane serial-dots 64 elems.
    int wv = threadIdx.x >> 6;
    int l  = threadIdx.x & 63;
    int d    = l & 31;
    int half = l >> 5;
    for (int q = 0; q < 4; ++q) {
        int tn = wv * 4 + q;
        int n = n0 + tn;
        int ai = adj[n * DD + d];          // coalesced (both halves hit same 128B)
        int rd = rel[n * DD + d];
        int row = (ai > 0) ? (ai - 1) : 0; // load row 0 harmlessly when padded
        const float* xb = center + (size_t)row * UC + half * 64;
        int qbase = (tn * 8 + rd) * 128;
        int coff  = rd * 4;
        float s = 0.f;
        #pragma unroll
        for (int k = 0; k < 16; ++k) {
            float4 x4 = *(const float4*)&xb[k * 4];
            float4 q4 = *(const float4*)&qr_s[qbase + ((half * 64 + k * 4 + coff) & 127)];
            s += x4.x * q4.x + x4.y * q4.y + x4.z * q4.z + x4.w * q4.w;
        }
        s += __shfl_xor(s, 32, 64);        // merge halves; both halves now hold full dot
        if (ai == 0) s = 0.f;              // padded neighbor row is zeros
        if (rd == 0) s = -1e9f;            // padded edge mask
        float mx = s;
        #pragma unroll
        for (int off = 16; off > 0; off >>= 1)
            mx = fmaxf(mx, __shfl_xor(mx, off, 64));   // stays within each 32-group
        float ex = __expf(s - mx);
        float sm = ex;
        #pragma unroll
        for (int off = 16; off > 0; off >>= 1)
            sm += __shfl_xor(sm, off, 64);
        if (l < 32) attn[n * DD + l] = ex / sm;
    }
}

// ---------- fused: reg-accumulated buckets, agg = sum_r bucket_r @ RV[r], fc ----------
__global__ void k_agg(const float* __restrict__ center, const float* __restrict__ RVmat,
                      const float* __restrict__ fcw, const float* __restrict__ fcb,
                      const int* __restrict__ adj, const int* __restrict__ rel,
                      const float* __restrict__ attn, float* __restrict__ out) {
    __shared__ float bucket[16 * 8 * 128];   // 64 KB, later reused for agg
    int n0 = blockIdx.x * 16;
    int j = threadIdx.x & 127, h = threadIdx.x >> 7;

    // bucket accumulation in registers; rd is wave-uniform -> scalar branch, 1 FMA/edge
    float bk[8][8];
    #pragma unroll
    for (int nn = 0; nn < 8; ++nn)
        #pragma unroll
        for (int r = 0; r < 8; ++r) bk[nn][r] = 0.f;

    for (int nn = 0; nn < 8; ++nn) {
        int tn = h * 8 + nn;
        int n = n0 + tn;
        const int* arow = adj + n * DD;
        const int* rrow = rel + n * DD;
        const float* at = attn + n * DD;
        for (int d = 0; d < 32; ++d) {
            int rd = __builtin_amdgcn_readfirstlane(rrow[d]);   // wave-uniform
            int ai = arow[d];
            float a = at[d];
            float xv = (ai > 0) ? center[(size_t)(ai - 1) * UC + j] : 0.f;
            float t = a * xv;
            switch (rd) {
                case 0: bk[nn][0] += t; break;
                case 1: bk[nn][1] += t; break;
                case 2: bk[nn][2] += t; break;
                case 3: bk[nn][3] += t; break;
                case 4: bk[nn][4] += t; break;
                case 5: bk[nn][5] += t; break;
                case 6: bk[nn][6] += t; break;
                case 7: bk[nn][7] += t; break;
            }
        }
    }
    #pragma unroll
    for (int nn = 0; nn < 8; ++nn)
        #pragma unroll
        for (int r = 0; r < 8; ++r)
            bucket[((h * 8 + nn) * 8 + r) * 128 + j] = bk[nn][r];
    __syncthreads();

    float acc[8];
    #pragma unroll
    for (int nn = 0; nn < 8; ++nn) acc[nn] = 0.f;
    for (int r = 0; r < 8; ++r) {
        for (int kc = 0; kc < 32; ++kc) {
            float4 bv[8];
            #pragma unroll
            for (int nn = 0; nn < 8; ++nn)
                bv[nn] = *(const float4*)&bucket[((h * 8 + nn) * 8 + r) * 128 + kc * 4];
            #pragma unroll
            for (int kk = 0; kk < 4; ++kk) {
                float w = RVmat[(r * UC + kc * 4 + kk) * UC + j];
                #pragma unroll
                for (int nn = 0; nn < 8; ++nn)
                    acc[nn] += ((const float*)&bv[nn])[kk] * w;
            }
        }
    }
    __syncthreads();
    float* agg_s = bucket;   // overlay
    #pragma unroll
    for (int nn = 0; nn < 8; ++nn) agg_s[(h * 8 + nn) * 128 + j] = acc[nn];
    __syncthreads();

    float acc2[8];
    #pragma unroll
    for (int nn = 0; nn < 8; ++nn) acc2[nn] = 0.f;
    for (int kc = 0; kc < 32; ++kc) {
        float4 av[8];
        #pragma unroll
        for (int nn = 0; nn < 8; ++nn)
            av[nn] = *(const float4*)&agg_s[(h * 8 + nn) * 128 + kc * 4];
        #pragma unroll
        for (int kk = 0; kk < 4; ++kk) {
            float w = fcw[(kc * 4 + kk) * UC + j];
            #pragma unroll
            for (int nn = 0; nn < 8; ++nn)
                acc2[nn] += ((const float*)&av[nn])[kk] * w;
        }
    }
    float b = fcb[j];
    #pragma unroll
    for (int nn = 0; nn < 8; ++nn) {
        int n = n0 + h * 8 + nn;
        float v = acc2[nn] + b;
        v = v > 0.f ? v : 0.f;
        out[n * UC + j] = center[n * UC + j] + v;
    }
}

extern "C" void kernel_launch(void* const* d_in, const int* in_sizes, int n_in,
                              void* d_out, int out_size, void* d_ws, size_t ws_size,
                              hipStream_t stream) {
    const float* node_state = (const float*)d_in[0];
    const int*   adjacency  = (const int*)d_in[1];
    const int*   point_enc  = (const int*)d_in[2];
    const int*   relation   = (const int*)d_in[3];
    const float* pew        = (const float*)d_in[4];
    const float* relw       = (const float*)d_in[5];
    const float* qw         = (const float*)d_in[6];
    const float* kw         = (const float*)d_in[7];
    const float* vw         = (const float*)d_in[8];
    const float* fcw        = (const float*)d_in[9];
    const float* fcb        = (const float*)d_in[10];
    float* out = (float*)d_out;

    float* P      = (float*)d_ws;                  // 128*128
    float* Mmat   = P + 128 * 128;                 // 8*128*128
    float* RVmat  = Mmat + 8 * 128 * 128;          // 8*128*128
    float* center = RVmat + 8 * 128 * 128;         // N*128
    float* attn   = center + (size_t)NNODE * UC;   // N*32
    int*   cnt    = (int*)(attn + (size_t)NNODE * DD);
    int*   basep  = cnt + 8;
    int*   cnt2   = basep + 8;
    int*   list   = cnt2 + 8;                      // N ints

    hipMemsetAsync(cnt, 0, 24 * sizeof(int), stream);
    k_qkt<<<64, 256, 0, stream>>>(qw, kw, P);
    k_mrv<<<dim3(8, 8), 256, 0, stream>>>(P, relw, vw, Mmat, RVmat);
    k_count<<<NNODE / 256, 256, 0, stream>>>(point_enc, cnt);
    k_scan<<<1, 64, 0, stream>>>(cnt, basep);
    k_scatter<<<NNODE / 256, 256, 0, stream>>>(point_enc, basep, cnt2, list);
    k_center<<<dim3(NNODE / 32, EC), 256, 0, stream>>>(node_state, pew, list, cnt, basep, center);
    k_scores<<<NNODE / 16, 256, 0, stream>>>(center, Mmat, adjacency, relation, attn);
    k_agg<<<NNODE / 16, 256, 0, stream>>>(center, RVmat, fcw, fcb, adjacency, relation, attn, out);
}

// Round 3
// 861.195 us; speedup vs baseline: 1.1720x; 1.1720x over previous
//
#include <hip/hip_runtime.h>

#define NNODE 16384
#define DD 32
#define INPC 256
#define UC 128
#define RC 8
#define EC 8

// ---------- prep: P = (q_w @ k_w^T) / U ----------
__global__ void k_qkt(const float* __restrict__ qw, const float* __restrict__ kw,
                      float* __restrict__ P) {
    int id = blockIdx.x * 256 + threadIdx.x;
    int i = id >> 7, j = id & 127;
    const float4* qr = (const float4*)(qw + i * UC);
    const float4* kr = (const float4*)(kw + j * UC);
    float acc = 0.f;
    #pragma unroll
    for (int lc = 0; lc < 32; ++lc) {
        float4 a = qr[lc], b = kr[lc];
        acc += a.x * b.x + a.y * b.y + a.z * b.z + a.w * b.w;
    }
    P[id] = acc * (1.0f / 128.0f);
}

// ---------- prep: BallQ[i*1024 + r*128 + j] = (P @ rel_w[r]^T)[i][j]
//             RVB[(r*128+i)*128 + j] = (rel_w[r] @ v_w)[i][j] ----------
__global__ void k_mrv(const float* __restrict__ P, const float* __restrict__ relw,
                      const float* __restrict__ vw, float* __restrict__ BallQ,
                      float* __restrict__ RVB) {
    int r = blockIdx.x, i0 = blockIdx.y * 16;
    const float* R = relw + r * UC * UC;
    int j = threadIdx.x & 127, h = threadIdx.x >> 7;

    float accM[8] = {0,0,0,0,0,0,0,0};
    for (int mc = 0; mc < 32; ++mc) {
        float4 rv = *(const float4*)&R[j * UC + mc * 4];
        #pragma unroll
        for (int ii = 0; ii < 8; ++ii) {
            float4 p = *(const float4*)&P[(i0 + h * 8 + ii) * UC + mc * 4];
            accM[ii] += p.x * rv.x + p.y * rv.y + p.z * rv.z + p.w * rv.w;
        }
    }
    #pragma unroll
    for (int ii = 0; ii < 8; ++ii)
        BallQ[(i0 + h * 8 + ii) * 1024 + r * 128 + j] = accM[ii];

    float accV[8] = {0,0,0,0,0,0,0,0};
    for (int m = 0; m < UC; ++m) {
        float v = vw[m * UC + j];
        #pragma unroll
        for (int ii = 0; ii < 8; ++ii)
            accV[ii] += R[(i0 + h * 8 + ii) * UC + m] * v;
    }
    #pragma unroll
    for (int ii = 0; ii < 8; ++ii)
        RVB[(r * 128 + i0 + h * 8 + ii) * 128 + j] = accV[ii];
}

// ---------- compaction by entity ----------
__global__ void k_count(const int* __restrict__ pe, int* __restrict__ cnt) {
    int n = blockIdx.x * 256 + threadIdx.x;
    atomicAdd(&cnt[pe[n]], 1);
}
__global__ void k_scan(const int* __restrict__ cnt, int* __restrict__ base) {
    if (threadIdx.x == 0) {
        int run = 0;
        for (int e = 0; e < EC; ++e) { base[e] = run; run += cnt[e]; }
    }
}
__global__ void k_scatter(const int* __restrict__ pe, const int* __restrict__ base,
                          int* __restrict__ cnt2, int* __restrict__ list) {
    int n = blockIdx.x * 256 + threadIdx.x;
    int e = pe[n];
    int pos = base[e] + atomicAdd(&cnt2[e], 1);
    list[pos] = n;
}

// ---------- center[n] = node_state[n] @ point_enc_w[pe[n]] ----------
__global__ void k_center(const float* __restrict__ ns, const float* __restrict__ pew,
                         const int* __restrict__ list, const int* __restrict__ cnt,
                         const int* __restrict__ base, float* __restrict__ center) {
    int e = blockIdx.y;
    int start = blockIdx.x * 32;
    int c = cnt[e];
    if (start >= c) return;
    int m = min(32, c - start);

    __shared__ float ns_s[32 * 256];   // 32 KB
    __shared__ int ids_s[32];
    if ((int)threadIdx.x < m) ids_s[threadIdx.x] = list[base[e] + start + threadIdx.x];
    __syncthreads();
    for (int idx = threadIdx.x; idx < m * 256; idx += 256)
        ns_s[idx] = ns[ids_s[idx >> 8] * INPC + (idx & 255)];
    __syncthreads();

    int j = threadIdx.x & 127, h = threadIdx.x >> 7;
    const float* W = pew + (size_t)e * INPC * UC;
    float acc[16];
    #pragma unroll
    for (int rr = 0; rr < 16; ++rr) acc[rr] = 0.f;

    for (int kc = 0; kc < 64; ++kc) {
        float w0 = W[(kc * 4 + 0) * UC + j];
        float w1 = W[(kc * 4 + 1) * UC + j];
        float w2 = W[(kc * 4 + 2) * UC + j];
        float w3 = W[(kc * 4 + 3) * UC + j];
        #pragma unroll
        for (int rr = 0; rr < 16; ++rr) {
            float4 nv = *(const float4*)&ns_s[(h * 16 + rr) * 256 + kc * 4];
            acc[rr] += nv.x * w0 + nv.y * w1 + nv.z * w2 + nv.w * w3;
        }
    }
    #pragma unroll
    for (int rr = 0; rr < 16; ++rr) {
        int row = h * 16 + rr;
        if (row < m) center[ids_s[row] * UC + j] = acc[rr];
    }
}

// ---------- qr[n, r*128+j] = center[n] @ BallQ  (dense GEMM, no LDS) ----------
__global__ __launch_bounds__(256, 4)
void k_qr(const float* __restrict__ center, const float* __restrict__ B,
          float* __restrict__ qr) {
    int n0 = blockIdx.x * 16;
    int j = threadIdx.x & 127, h = threadIdx.x >> 7;

    float acc[8][8];   // [r][nn]
    #pragma unroll
    for (int r = 0; r < 8; ++r)
        #pragma unroll
        for (int nn = 0; nn < 8; ++nn) acc[r][nn] = 0.f;

    for (int kc = 0; kc < 32; ++kc) {
        float4 cv[8];
        #pragma unroll
        for (int nn = 0; nn < 8; ++nn)
            cv[nn] = *(const float4*)&center[(n0 + h * 8 + nn) * UC + kc * 4];
        #pragma unroll
        for (int kk = 0; kk < 4; ++kk) {
            #pragma unroll
            for (int r = 0; r < 8; ++r) {
                float w = B[(kc * 4 + kk) * 1024 + r * 128 + j];   // coalesced, L2-hot
                #pragma unroll
                for (int nn = 0; nn < 8; ++nn)
                    acc[r][nn] += ((const float*)&cv[nn])[kk] * w;
            }
        }
    }
    #pragma unroll
    for (int r = 0; r < 8; ++r)
        #pragma unroll
        for (int nn = 0; nn < 8; ++nn)
            qr[(size_t)(n0 + h * 8 + nn) * 1024 + r * 128 + j] = acc[r][nn];
}

// ---------- scores + softmax: edge-parallel, no LDS ----------
__global__ void k_att(const float* __restrict__ center, const float* __restrict__ qr,
                      const int* __restrict__ adj, const int* __restrict__ rel,
                      float* __restrict__ attn) {
    int wv = threadIdx.x >> 6, l = threadIdx.x & 63;
    int d = l & 31, half = l >> 5;
    int nbase = blockIdx.x * 16 + wv * 4;
    for (int q = 0; q < 4; ++q) {
        int n = nbase + q;
        int ai = adj[n * DD + d];
        int rd = rel[n * DD + d];
        int row = ai > 0 ? ai - 1 : 0;
        const float* xb = center + (size_t)row * UC + half * 64;
        const float* qb = qr + (size_t)n * 1024 + rd * 128 + half * 64;
        float s = 0.f;
        #pragma unroll
        for (int k = 0; k < 16; ++k) {
            float4 x4 = *(const float4*)&xb[k * 4];
            float4 q4 = *(const float4*)&qb[k * 4];
            s += x4.x * q4.x + x4.y * q4.y + x4.z * q4.z + x4.w * q4.w;
        }
        s += __shfl_xor(s, 32, 64);        // merge halves
        if (ai == 0) s = 0.f;              // zero neighbor row -> score 0
        if (rd == 0) s = -1e9f;            // padded edge mask
        float mx = s;
        #pragma unroll
        for (int off = 16; off > 0; off >>= 1)
            mx = fmaxf(mx, __shfl_xor(mx, off, 64));
        float ex = __expf(s - mx);
        float sm = ex;
        #pragma unroll
        for (int off = 16; off > 0; off >>= 1)
            sm += __shfl_xor(sm, off, 64);
        if (l < 32) attn[n * DD + l] = ex / sm;
    }
}

// ---------- buckets: branchless predicated accumulate, registers only ----------
__global__ void k_bucket(const float* __restrict__ center, const int* __restrict__ adj,
                         const int* __restrict__ rel, const float* __restrict__ attn,
                         float* __restrict__ bucketA) {
    int wv = threadIdx.x >> 6, l = threadIdx.x & 63;
    int nbase = blockIdx.x * 16 + wv * 4;
    for (int q = 0; q < 4; ++q) {
        int n = nbase + q;
        float bk0[8], bk1[8];
        #pragma unroll
        for (int r = 0; r < 8; ++r) { bk0[r] = 0.f; bk1[r] = 0.f; }
        const int* arow = adj + n * DD;
        const int* rrow = rel + n * DD;
        const float* at = attn + n * DD;
        #pragma unroll 4
        for (int d = 0; d < 32; ++d) {
            int ai = arow[d];
            int rd = rrow[d];
            float a = at[d];
            a = ai > 0 ? a : 0.f;                 // adj==0 contributes exactly 0
            int row = ai > 0 ? ai - 1 : 0;
            const float* xp = center + (size_t)row * UC;
            float t0 = a * xp[l];
            float t1 = a * xp[l + 64];
            #pragma unroll
            for (int r = 0; r < 8; ++r) {
                bool m = (rd == r);
                bk0[r] += m ? t0 : 0.f;           // cndmask + fma, no branch
                bk1[r] += m ? t1 : 0.f;
            }
        }
        #pragma unroll
        for (int r = 0; r < 8; ++r) {
            bucketA[(size_t)n * 1024 + r * 128 + l]      = bk0[r];
            bucketA[(size_t)n * 1024 + r * 128 + l + 64] = bk1[r];
        }
    }
}

// ---------- agg = bucketA @ RVB, then out = center + relu(agg@fcw + b) ----------
__global__ __launch_bounds__(256, 4)
void k_out(const float* __restrict__ bucketA, const float* __restrict__ RVB,
           const float* __restrict__ fcw, const float* __restrict__ fcb,
           const float* __restrict__ center, float* __restrict__ out) {
    __shared__ float agg_s[32 * 128];   // 16 KB
    int n0 = blockIdx.x * 32;
    int j = threadIdx.x & 127, h = threadIdx.x >> 7;

    float acc[16];
    #pragma unroll
    for (int rr = 0; rr < 16; ++rr) acc[rr] = 0.f;

    for (int kb = 0; kb < 256; ++kb) {
        float w0 = RVB[(kb * 4 + 0) * 128 + j];
        float w1 = RVB[(kb * 4 + 1) * 128 + j];
        float w2 = RVB[(kb * 4 + 2) * 128 + j];
        float w3 = RVB[(kb * 4 + 3) * 128 + j];
        #pragma unroll
        for (int rr = 0; rr < 16; ++rr) {
            float4 a4 = *(const float4*)&bucketA[(size_t)(n0 + h * 16 + rr) * 1024 + kb * 4];
            acc[rr] += a4.x * w0 + a4.y * w1 + a4.z * w2 + a4.w * w3;
        }
    }
    #pragma unroll
    for (int rr = 0; rr < 16; ++rr) agg_s[(h * 16 + rr) * 128 + j] = acc[rr];
    __syncthreads();

    float acc2[16];
    #pragma unroll
    for (int rr = 0; rr < 16; ++rr) acc2[rr] = 0.f;
    for (int kc = 0; kc < 32; ++kc) {
        float w0 = fcw[(kc * 4 + 0) * 128 + j];
        float w1 = fcw[(kc * 4 + 1) * 128 + j];
        float w2 = fcw[(kc * 4 + 2) * 128 + j];
        float w3 = fcw[(kc * 4 + 3) * 128 + j];
        #pragma unroll
        for (int rr = 0; rr < 16; ++rr) {
            float4 a4 = *(const float4*)&agg_s[(h * 16 + rr) * 128 + kc * 4];
            acc2[rr] += a4.x * w0 + a4.y * w1 + a4.z * w2 + a4.w * w3;
        }
    }
    float b = fcb[j];
    #pragma unroll
    for (int rr = 0; rr < 16; ++rr) {
        int n = n0 + h * 16 + rr;
        float v = acc2[rr] + b;
        v = v > 0.f ? v : 0.f;
        out[n * 128 + j] = center[n * 128 + j] + v;
    }
}

extern "C" void kernel_launch(void* const* d_in, const int* in_sizes, int n_in,
                              void* d_out, int out_size, void* d_ws, size_t ws_size,
                              hipStream_t stream) {
    const float* node_state = (const float*)d_in[0];
    const int*   adjacency  = (const int*)d_in[1];
    const int*   point_enc  = (const int*)d_in[2];
    const int*   relation   = (const int*)d_in[3];
    const float* pew        = (const float*)d_in[4];
    const float* relw       = (const float*)d_in[5];
    const float* qw         = (const float*)d_in[6];
    const float* kw         = (const float*)d_in[7];
    const float* vw         = (const float*)d_in[8];
    const float* fcw        = (const float*)d_in[9];
    const float* fcb        = (const float*)d_in[10];
    float* out = (float*)d_out;

    float* P      = (float*)d_ws;                    // 128*128
    float* BallQ  = P + 128 * 128;                   // 128*1024
    float* RVB    = BallQ + 128 * 1024;              // 1024*128
    float* center = RVB + 1024 * 128;                // N*128
    float* attn   = center + (size_t)NNODE * UC;     // N*32
    int*   cnt    = (int*)(attn + (size_t)NNODE * DD);
    int*   basep  = cnt + 8;
    int*   cnt2   = basep + 8;
    int*   list   = cnt2 + 8;                        // N ints
    float* qr     = (float*)(list + NNODE);          // N*1024 (67 MB)
    float* bucketA = qr;                             // overlay: qr dead after k_att

    hipMemsetAsync(cnt, 0, 24 * sizeof(int), stream);
    k_qkt<<<64, 256, 0, stream>>>(qw, kw, P);
    k_mrv<<<dim3(8, 8), 256, 0, stream>>>(P, relw, vw, BallQ, RVB);
    k_count<<<NNODE / 256, 256, 0, stream>>>(point_enc, cnt);
    k_scan<<<1, 64, 0, stream>>>(cnt, basep);
    k_scatter<<<NNODE / 256, 256, 0, stream>>>(point_enc, basep, cnt2, list);
    k_center<<<dim3(NNODE / 32, EC), 256, 0, stream>>>(node_state, pew, list, cnt, basep, center);
    k_qr<<<NNODE / 16, 256, 0, stream>>>(center, BallQ, qr);
    k_att<<<NNODE / 16, 256, 0, stream>>>(center, qr, adjacency, relation, attn);
    k_bucket<<<NNODE / 16, 256, 0, stream>>>(center, adjacency, relation, attn, bucketA);
    k_out<<<NNODE / 32, 256, 0, stream>>>(bucketA, RVB, fcw, fcb, center, out);
}

// Round 4
// 448.920 us; speedup vs baseline: 2.2484x; 1.9184x over previous
//
#include <hip/hip_runtime.h>

#define NNODE 16384
#define DD 32
#define INPC 256
#define UC 128
#define RC 8
#define EC 8

typedef __attribute__((ext_vector_type(8))) short short8;
typedef __attribute__((ext_vector_type(4))) float float4v;

__device__ __forceinline__ unsigned short f2bf(float f) {
    unsigned u = __builtin_bit_cast(unsigned, f);
    unsigned r = (u + 0x7FFFu + ((u >> 16) & 1u)) >> 16;   // RNE
    return (unsigned short)r;
}
__device__ __forceinline__ float bflo(unsigned u) { return __builtin_bit_cast(float, u << 16); }
__device__ __forceinline__ float bfhi(unsigned u) { return __builtin_bit_cast(float, u & 0xFFFF0000u); }
__device__ __forceinline__ float bf2f(unsigned short s) { return __builtin_bit_cast(float, (unsigned)s << 16); }

// B-fragment flat index for mfma_f32_16x16x32_bf16: B[k][col], lane l holds
// k=(l>>4)*8+jj, n=l&15.  nct = #16-col tiles.
__device__ __forceinline__ int bfrag_idx(int k, int col, int nct) {
    int ks = k >> 5, ct = col >> 4;
    int l = (((k >> 3) & 3) << 4) | (col & 15);
    return (((ks * nct + ct) << 6) + l) * 8 + (k & 7);
}

// ---------- prep: P = (q_w @ k_w^T) / U ----------
__global__ void k_qkt(const float* __restrict__ qw, const float* __restrict__ kw,
                      float* __restrict__ P) {
    int id = blockIdx.x * 256 + threadIdx.x;
    int i = id >> 7, j = id & 127;
    const float4* qr = (const float4*)(qw + i * UC);
    const float4* kr = (const float4*)(kw + j * UC);
    float acc = 0.f;
    #pragma unroll
    for (int lc = 0; lc < 32; ++lc) {
        float4 a = qr[lc], b = kr[lc];
        acc += a.x * b.x + a.y * b.y + a.z * b.z + a.w * b.w;
    }
    P[id] = acc * (1.0f / 128.0f);
}

// ---------- prep: BallQfrag = frag(P @ rel_w[r]^T), RVBfrag = frag(rel_w[r] @ v_w) ----------
__global__ void k_mrv(const float* __restrict__ P, const float* __restrict__ relw,
                      const float* __restrict__ vw, unsigned short* __restrict__ BallQfrag,
                      unsigned short* __restrict__ RVBfrag) {
    int r = blockIdx.x, i0 = blockIdx.y * 16;
    const float* R = relw + r * UC * UC;
    int j = threadIdx.x & 127, h = threadIdx.x >> 7;

    float accM[8] = {0,0,0,0,0,0,0,0};
    for (int mc = 0; mc < 32; ++mc) {
        float4 rv = *(const float4*)&R[j * UC + mc * 4];
        #pragma unroll
        for (int ii = 0; ii < 8; ++ii) {
            float4 p = *(const float4*)&P[(i0 + h * 8 + ii) * UC + mc * 4];
            accM[ii] += p.x * rv.x + p.y * rv.y + p.z * rv.z + p.w * rv.w;
        }
    }
    #pragma unroll
    for (int ii = 0; ii < 8; ++ii) {
        int i = i0 + h * 8 + ii;
        BallQfrag[bfrag_idx(i, r * 128 + j, 64)] = f2bf(accM[ii]);   // k=i, col=r*128+j
    }

    float accV[8] = {0,0,0,0,0,0,0,0};
    for (int m = 0; m < UC; ++m) {
        float v = vw[m * UC + j];
        #pragma unroll
        for (int ii = 0; ii < 8; ++ii)
            accV[ii] += R[(i0 + h * 8 + ii) * UC + m] * v;
    }
    #pragma unroll
    for (int ii = 0; ii < 8; ++ii) {
        int i = i0 + h * 8 + ii;
        RVBfrag[bfrag_idx(r * 128 + i, j, 8)] = f2bf(accV[ii]);      // k=r*128+i, col=j
    }
}

// ---------- compaction by entity ----------
__global__ void k_count(const int* __restrict__ pe, int* __restrict__ cnt) {
    int n = blockIdx.x * 256 + threadIdx.x;
    atomicAdd(&cnt[pe[n]], 1);
}
__global__ void k_scan(const int* __restrict__ cnt, int* __restrict__ base) {
    if (threadIdx.x == 0) {
        int run = 0;
        for (int e = 0; e < EC; ++e) { base[e] = run; run += cnt[e]; }
    }
}
__global__ void k_scatter(const int* __restrict__ pe, const int* __restrict__ base,
                          int* __restrict__ cnt2, int* __restrict__ list) {
    int n = blockIdx.x * 256 + threadIdx.x;
    int e = pe[n];
    int pos = base[e] + atomicAdd(&cnt2[e], 1);
    list[pos] = n;
}

// ---------- center_bf[n] = bf16(node_state[n] @ point_enc_w[pe[n]]) ----------
__global__ void k_center(const float* __restrict__ ns, const float* __restrict__ pew,
                         const int* __restrict__ list, const int* __restrict__ cnt,
                         const int* __restrict__ base, unsigned short* __restrict__ center_bf) {
    int e = blockIdx.y;
    int start = blockIdx.x * 32;
    int c = cnt[e];
    if (start >= c) return;
    int m = min(32, c - start);

    __shared__ float ns_s[32 * 256];   // 32 KB
    __shared__ int ids_s[32];
    if ((int)threadIdx.x < m) ids_s[threadIdx.x] = list[base[e] + start + threadIdx.x];
    __syncthreads();
    for (int idx = threadIdx.x; idx < m * 256; idx += 256)
        ns_s[idx] = ns[ids_s[idx >> 8] * INPC + (idx & 255)];
    __syncthreads();

    int j = threadIdx.x & 127, h = threadIdx.x >> 7;
    const float* W = pew + (size_t)e * INPC * UC;
    float acc[16];
    #pragma unroll
    for (int rr = 0; rr < 16; ++rr) acc[rr] = 0.f;

    for (int kc = 0; kc < 64; ++kc) {
        float w0 = W[(kc * 4 + 0) * UC + j];
        float w1 = W[(kc * 4 + 1) * UC + j];
        float w2 = W[(kc * 4 + 2) * UC + j];
        float w3 = W[(kc * 4 + 3) * UC + j];
        #pragma unroll
        for (int rr = 0; rr < 16; ++rr) {
            float4 nv = *(const float4*)&ns_s[(h * 16 + rr) * 256 + kc * 4];
            acc[rr] += nv.x * w0 + nv.y * w1 + nv.z * w2 + nv.w * w3;
        }
    }
    #pragma unroll
    for (int rr = 0; rr < 16; ++rr) {
        int row = h * 16 + rr;
        if (row < m) center_bf[ids_s[row] * UC + j] = f2bf(acc[rr]);
    }
}

// ---------- qr[n, r*128+u] = center_bf @ BallQ   (MFMA, bf16) ----------
__global__ __launch_bounds__(256)
void k_qr(const unsigned short* __restrict__ center_bf,
          const unsigned short* __restrict__ Bfrag,
          unsigned short* __restrict__ qr) {
    int w = threadIdx.x >> 6, l = threadIdx.x & 63;
    int n0 = blockIdx.x * 128 + w * 32;
    int ct0 = blockIdx.y * 4;                 // 4 col-tiles = 64 cols
    float4v acc[2][4] = {};
    #pragma unroll
    for (int ks = 0; ks < 4; ++ks) {
        short8 a[2], b[4];
        #pragma unroll
        for (int mi = 0; mi < 2; ++mi) {
            int row = n0 + mi * 16 + (l & 15);
            a[mi] = *(const short8*)&center_bf[row * 128 + ks * 32 + ((l >> 4) << 3)];
        }
        #pragma unroll
        for (int ci = 0; ci < 4; ++ci)
            b[ci] = *(const short8*)&Bfrag[(((ks * 64 + ct0 + ci) << 6) + l) * 8];
        #pragma unroll
        for (int mi = 0; mi < 2; ++mi)
            #pragma unroll
            for (int ci = 0; ci < 4; ++ci)
                acc[mi][ci] = __builtin_amdgcn_mfma_f32_16x16x32_bf16(a[mi], b[ci], acc[mi][ci], 0, 0, 0);
    }
    #pragma unroll
    for (int mi = 0; mi < 2; ++mi)
        #pragma unroll
        for (int ci = 0; ci < 4; ++ci)
            #pragma unroll
            for (int reg = 0; reg < 4; ++reg) {
                int row = n0 + mi * 16 + ((l >> 4) << 2) + reg;
                int col = (ct0 + ci) * 16 + (l & 15);
                qr[(size_t)row * 1024 + col] = f2bf(acc[mi][ci][reg]);
            }
}

// ---------- scores + softmax (bf16 gathers) ----------
__global__ void k_att(const unsigned short* __restrict__ center_bf,
                      const unsigned short* __restrict__ qr,
                      const int* __restrict__ adj, const int* __restrict__ rel,
                      float* __restrict__ attn) {
    int wv = threadIdx.x >> 6, l = threadIdx.x & 63;
    int d = l & 31, half = l >> 5;
    int nbase = blockIdx.x * 16 + wv * 4;
    for (int q = 0; q < 4; ++q) {
        int n = nbase + q;
        int ai = adj[n * DD + d];
        int rd = rel[n * DD + d];
        int row = ai > 0 ? ai - 1 : 0;
        const unsigned short* xb = center_bf + (size_t)row * 128 + half * 64;
        const unsigned short* qb = qr + (size_t)n * 1024 + rd * 128 + half * 64;
        float s = 0.f;
        #pragma unroll
        for (int k = 0; k < 8; ++k) {
            uint2 xu = *(const uint2*)&xb[k * 8 + 0];
            uint2 qu = *(const uint2*)&qb[k * 8 + 0];
            uint2 xv = *(const uint2*)&xb[k * 8 + 4];
            uint2 qv = *(const uint2*)&qb[k * 8 + 4];
            s += bflo(xu.x) * bflo(qu.x) + bfhi(xu.x) * bfhi(qu.x);
            s += bflo(xu.y) * bflo(qu.y) + bfhi(xu.y) * bfhi(qu.y);
            s += bflo(xv.x) * bflo(qv.x) + bfhi(xv.x) * bfhi(qv.x);
            s += bflo(xv.y) * bflo(qv.y) + bfhi(xv.y) * bfhi(qv.y);
        }
        s += __shfl_xor(s, 32, 64);        // merge halves
        if (ai == 0) s = 0.f;
        if (rd == 0) s = -1e9f;
        float mx = s;
        #pragma unroll
        for (int off = 16; off > 0; off >>= 1)
            mx = fmaxf(mx, __shfl_xor(mx, off, 64));
        float ex = __expf(s - mx);
        float sm = ex;
        #pragma unroll
        for (int off = 16; off > 0; off >>= 1)
            sm += __shfl_xor(sm, off, 64);
        if (l < 32) attn[n * DD + l] = ex / sm;
    }
}

// ---------- buckets (bf16 in/out, predicated register accumulate) ----------
__global__ void k_bucket(const unsigned short* __restrict__ center_bf,
                         const int* __restrict__ adj, const int* __restrict__ rel,
                         const float* __restrict__ attn, unsigned short* __restrict__ bucketA) {
    int wv = threadIdx.x >> 6, l = threadIdx.x & 63;
    int nbase = blockIdx.x * 16 + wv * 4;
    for (int q = 0; q < 4; ++q) {
        int n = nbase + q;
        float bk0[8], bk1[8];
        #pragma unroll
        for (int r = 0; r < 8; ++r) { bk0[r] = 0.f; bk1[r] = 0.f; }
        const int* arow = adj + n * DD;
        const int* rrow = rel + n * DD;
        const float* at = attn + n * DD;
        #pragma unroll 4
        for (int d = 0; d < 32; ++d) {
            int ai = arow[d];
            int rd = rrow[d];
            float a = at[d];
            a = ai > 0 ? a : 0.f;
            int row = ai > 0 ? ai - 1 : 0;
            unsigned xu = *(const unsigned*)&center_bf[(size_t)row * 128 + l * 2];
            float t0 = a * bflo(xu), t1 = a * bfhi(xu);
            #pragma unroll
            for (int r = 0; r < 8; ++r) {
                bool m = (rd == r);
                bk0[r] += m ? t0 : 0.f;
                bk1[r] += m ? t1 : 0.f;
            }
        }
        #pragma unroll
        for (int r = 0; r < 8; ++r) {
            unsigned pk = (unsigned)f2bf(bk0[r]) | ((unsigned)f2bf(bk1[r]) << 16);
            *(unsigned*)&bucketA[(size_t)n * 1024 + r * 128 + l * 2] = pk;
        }
    }
}

// ---------- agg = bucketA @ RVB (MFMA) ; out = center + relu(agg@fcw + b) ----------
__global__ __launch_bounds__(256)
void k_out(const unsigned short* __restrict__ Abf, const unsigned short* __restrict__ RVBfrag,
           const float* __restrict__ fcw, const float* __restrict__ fcb,
           const unsigned short* __restrict__ center_bf, float* __restrict__ out) {
    __shared__ float agg_s[16 * 132];   // ~8.25 KB
    int w = threadIdx.x >> 6, l = threadIdx.x & 63;
    int n0 = blockIdx.x * 16;
    float4v acc[2] = {};
    int arow = n0 + (l & 15);
    #pragma unroll 4
    for (int ks = 0; ks < 32; ++ks) {
        short8 a = *(const short8*)&Abf[(size_t)arow * 1024 + ks * 32 + ((l >> 4) << 3)];
        #pragma unroll
        for (int ci = 0; ci < 2; ++ci) {
            short8 b = *(const short8*)&RVBfrag[(((ks * 8 + w * 2 + ci) << 6) + l) * 8];
            acc[ci] = __builtin_amdgcn_mfma_f32_16x16x32_bf16(a, b, acc[ci], 0, 0, 0);
        }
    }
    #pragma unroll
    for (int ci = 0; ci < 2; ++ci)
        #pragma unroll
        for (int reg = 0; reg < 4; ++reg) {
            int row = ((l >> 4) << 2) + reg;
            int col = (w * 2 + ci) * 16 + (l & 15);
            agg_s[row * 132 + col] = acc[ci][reg];
        }
    __syncthreads();

    // phase 2: fc + relu + residual (fp32 VALU; agg rows broadcast from LDS)
    int j = threadIdx.x & 127, h = threadIdx.x >> 7;
    float acc2[8];
    #pragma unroll
    for (int rr = 0; rr < 8; ++rr) acc2[rr] = 0.f;
    for (int kc = 0; kc < 32; ++kc) {
        float w0 = fcw[(kc * 4 + 0) * 128 + j];
        float w1 = fcw[(kc * 4 + 1) * 128 + j];
        float w2 = fcw[(kc * 4 + 2) * 128 + j];
        float w3 = fcw[(kc * 4 + 3) * 128 + j];
        #pragma unroll
        for (int rr = 0; rr < 8; ++rr) {
            float4 a4 = *(const float4*)&agg_s[(h * 8 + rr) * 132 + kc * 4];
            acc2[rr] += a4.x * w0 + a4.y * w1 + a4.z * w2 + a4.w * w3;
        }
    }
    float b = fcb[j];
    #pragma unroll
    for (int rr = 0; rr < 8; ++rr) {
        int n = n0 + h * 8 + rr;
        float v = acc2[rr] + b;
        v = v > 0.f ? v : 0.f;
        out[(size_t)n * 128 + j] = bf2f(center_bf[(size_t)n * 128 + j]) + v;
    }
}

extern "C" void kernel_launch(void* const* d_in, const int* in_sizes, int n_in,
                              void* d_out, int out_size, void* d_ws, size_t ws_size,
                              hipStream_t stream) {
    const float* node_state = (const float*)d_in[0];
    const int*   adjacency  = (const int*)d_in[1];
    const int*   point_enc  = (const int*)d_in[2];
    const int*   relation   = (const int*)d_in[3];
    const float* pew        = (const float*)d_in[4];
    const float* relw       = (const float*)d_in[5];
    const float* qw         = (const float*)d_in[6];
    const float* kw         = (const float*)d_in[7];
    const float* vw         = (const float*)d_in[8];
    const float* fcw        = (const float*)d_in[9];
    const float* fcb        = (const float*)d_in[10];
    float* out = (float*)d_out;

    char* ws = (char*)d_ws;
    float* P                  = (float*)ws;                      ws += 128 * 128 * 4;      // 64 KB
    unsigned short* BallQfrag = (unsigned short*)ws;             ws += 128 * 1024 * 2;     // 256 KB
    unsigned short* RVBfrag   = (unsigned short*)ws;             ws += 1024 * 128 * 2;     // 256 KB
    unsigned short* center_bf = (unsigned short*)ws;             ws += (size_t)NNODE * 128 * 2;  // 4 MB
    float* attn               = (float*)ws;                      ws += (size_t)NNODE * 32 * 4;   // 2 MB
    int* cnt                  = (int*)ws;                        ws += 256;                // cnt/base/cnt2 + pad
    int* basep = cnt + 8;
    int* cnt2  = basep + 8;
    int* list                 = (int*)ws;                        ws += NNODE * 4;          // 64 KB
    unsigned short* qr        = (unsigned short*)ws;                                       // 33 MB
    unsigned short* bucketA   = qr;   // overlay: qr dead after k_att

    hipMemsetAsync(cnt, 0, 24 * sizeof(int), stream);
    k_qkt<<<64, 256, 0, stream>>>(qw, kw, P);
    k_mrv<<<dim3(8, 8), 256, 0, stream>>>(P, relw, vw, BallQfrag, RVBfrag);
    k_count<<<NNODE / 256, 256, 0, stream>>>(point_enc, cnt);
    k_scan<<<1, 64, 0, stream>>>(cnt, basep);
    k_scatter<<<NNODE / 256, 256, 0, stream>>>(point_enc, basep, cnt2, list);
    k_center<<<dim3(NNODE / 32, EC), 256, 0, stream>>>(node_state, pew, list, cnt, basep, center_bf);
    k_qr<<<dim3(NNODE / 128, 16), 256, 0, stream>>>(center_bf, BallQfrag, qr);
    k_att<<<NNODE / 16, 256, 0, stream>>>(center_bf, qr, adjacency, relation, attn);
    k_bucket<<<NNODE / 16, 256, 0, stream>>>(center_bf, adjacency, relation, attn, bucketA);
    k_out<<<NNODE / 16, 256, 0, stream>>>(bucketA, RVBfrag, fcw, fcb, center_bf, out);
}

// Round 5
// 287.500 us; speedup vs baseline: 3.5108x; 1.5615x over previous
//
#include <hip/hip_runtime.h>

#define NNODE 16384
#define DD 32
#define INPC 256
#define UC 128
#define RC 8
#define EC 8

typedef __attribute__((ext_vector_type(8))) short short8;
typedef __attribute__((ext_vector_type(4))) float float4v;

__device__ __forceinline__ unsigned short f2bf(float f) {
    unsigned u = __builtin_bit_cast(unsigned, f);
    unsigned r = (u + 0x7FFFu + ((u >> 16) & 1u)) >> 16;   // RNE
    return (unsigned short)r;
}
__device__ __forceinline__ float bflo(unsigned u) { return __builtin_bit_cast(float, u << 16); }
__device__ __forceinline__ float bfhi(unsigned u) { return __builtin_bit_cast(float, u & 0xFFFF0000u); }
__device__ __forceinline__ float bf2f(unsigned short s) { return __builtin_bit_cast(float, (unsigned)s << 16); }

// B-fragment flat index for mfma_f32_16x16x32_bf16. nct = #16-col tiles.
__device__ __forceinline__ int bfrag_idx(int k, int col, int nct) {
    int ks = k >> 5, ct = col >> 4;
    int l = (((k >> 3) & 3) << 4) | (col & 15);
    return (((ks * nct + ct) << 6) + l) * 8 + (k & 7);
}

// ---------- prep (fused): P rows in LDS, then BallQfrag / RVBfrag ----------
__global__ void k_prep(const float* __restrict__ qw, const float* __restrict__ kw,
                       const float* __restrict__ relw, const float* __restrict__ vw,
                       unsigned short* __restrict__ BallQfrag,
                       unsigned short* __restrict__ RVBfrag) {
    __shared__ float P_s[16 * 128];   // 8 KB
    int r = blockIdx.x, i0 = blockIdx.y * 16;
    int j = threadIdx.x & 127, h = threadIdx.x >> 7;

    // phase 0: P[i0+h*8+ii][j] = dot(qw_row, kw_row)/128
    {
        float acc[8] = {0,0,0,0,0,0,0,0};
        const float4* kr = (const float4*)(kw + j * UC);
        for (int lc = 0; lc < 32; ++lc) {
            float4 b = kr[lc];
            #pragma unroll
            for (int ii = 0; ii < 8; ++ii) {
                float4 a = *(const float4*)&qw[(i0 + h * 8 + ii) * UC + lc * 4];
                acc[ii] += a.x * b.x + a.y * b.y + a.z * b.z + a.w * b.w;
            }
        }
        #pragma unroll
        for (int ii = 0; ii < 8; ++ii)
            P_s[(h * 8 + ii) * 128 + j] = acc[ii] * (1.0f / 128.0f);
    }
    __syncthreads();

    const float* R = relw + r * UC * UC;
    float accM[8] = {0,0,0,0,0,0,0,0};
    for (int mc = 0; mc < 32; ++mc) {
        float4 rv = *(const float4*)&R[j * UC + mc * 4];
        #pragma unroll
        for (int ii = 0; ii < 8; ++ii) {
            float4 p = *(const float4*)&P_s[(h * 8 + ii) * 128 + mc * 4];
            accM[ii] += p.x * rv.x + p.y * rv.y + p.z * rv.z + p.w * rv.w;
        }
    }
    #pragma unroll
    for (int ii = 0; ii < 8; ++ii) {
        int i = i0 + h * 8 + ii;
        BallQfrag[bfrag_idx(i, r * 128 + j, 64)] = f2bf(accM[ii]);   // k=i, col=r*128+j
    }

    float accV[8] = {0,0,0,0,0,0,0,0};
    for (int m = 0; m < UC; ++m) {
        float v = vw[m * UC + j];
        #pragma unroll
        for (int ii = 0; ii < 8; ++ii)
            accV[ii] += R[(i0 + h * 8 + ii) * UC + m] * v;
    }
    #pragma unroll
    for (int ii = 0; ii < 8; ++ii) {
        int i = i0 + h * 8 + ii;
        RVBfrag[bfrag_idx(r * 128 + i, j, 8)] = f2bf(accV[ii]);      // k=r*128+i, col=j
    }
}

// ---------- compaction: block histogram -> scan -> rank scatter (no global atomics) ----------
__global__ void k_hist(const int* __restrict__ pe, int* __restrict__ blockhist) {
    __shared__ int hh[8];
    if (threadIdx.x < 8) hh[threadIdx.x] = 0;
    __syncthreads();
    int n = blockIdx.x * 256 + threadIdx.x;
    atomicAdd(&hh[pe[n]], 1);
    __syncthreads();
    if (threadIdx.x < 8) blockhist[blockIdx.x * 8 + threadIdx.x] = hh[threadIdx.x];
}

__global__ void k_scanoff(const int* __restrict__ blockhist, int* __restrict__ blockoff,
                          int* __restrict__ cnt, int* __restrict__ basep) {
    __shared__ int tot[8];
    int e = threadIdx.x;
    if (e < 8) {
        int run = 0;
        for (int b = 0; b < 64; ++b) run += blockhist[b * 8 + e];
        tot[e] = run;
        cnt[e] = run;
    }
    __syncthreads();
    if (e < 8) {
        int base = 0;
        for (int i = 0; i < e; ++i) base += tot[i];
        basep[e] = base;
        int run = base;
        for (int b = 0; b < 64; ++b) { blockoff[b * 8 + e] = run; run += blockhist[b * 8 + e]; }
    }
}

__global__ void k_scatter(const int* __restrict__ pe, const int* __restrict__ blockoff,
                          int* __restrict__ list) {
    __shared__ int wavecnt[4 * 8];
    int t = threadIdx.x, w = t >> 6, l = t & 63;
    int n = blockIdx.x * 256 + t;
    int e = pe[n];
    unsigned long long mymask = 0;
    #pragma unroll
    for (int r = 0; r < 8; ++r) {
        unsigned long long m = __ballot(e == r);
        if (e == r) mymask = m;
        if (l == r) wavecnt[w * 8 + r] = (int)__popcll(m);
    }
    __syncthreads();
    int off = 0;
    for (int w2 = 0; w2 < w; ++w2) off += wavecnt[w2 * 8 + e];
    unsigned long long ltmask = (1ull << l) - 1ull;
    int rank = (int)__popcll(mymask & ltmask);
    list[blockoff[blockIdx.x * 8 + e] + off + rank] = n;
}

// ---------- center_bf[n] = bf16(node_state[n] @ point_enc_w[pe[n]]) ----------
__global__ void k_center(const float* __restrict__ ns, const float* __restrict__ pew,
                         const int* __restrict__ list, const int* __restrict__ cnt,
                         const int* __restrict__ base, unsigned short* __restrict__ center_bf) {
    int e = blockIdx.y;
    int start = blockIdx.x * 32;
    int c = cnt[e];
    if (start >= c) return;
    int m = min(32, c - start);

    __shared__ float ns_s[32 * 256];   // 32 KB
    __shared__ int ids_s[32];
    if ((int)threadIdx.x < m) ids_s[threadIdx.x] = list[base[e] + start + threadIdx.x];
    __syncthreads();
    for (int idx = threadIdx.x; idx < m * 256; idx += 256)
        ns_s[idx] = ns[ids_s[idx >> 8] * INPC + (idx & 255)];
    __syncthreads();

    int j = threadIdx.x & 127, h = threadIdx.x >> 7;
    const float* W = pew + (size_t)e * INPC * UC;
    float acc[16];
    #pragma unroll
    for (int rr = 0; rr < 16; ++rr) acc[rr] = 0.f;

    for (int kc = 0; kc < 64; ++kc) {
        float w0 = W[(kc * 4 + 0) * UC + j];
        float w1 = W[(kc * 4 + 1) * UC + j];
        float w2 = W[(kc * 4 + 2) * UC + j];
        float w3 = W[(kc * 4 + 3) * UC + j];
        #pragma unroll
        for (int rr = 0; rr < 16; ++rr) {
            float4 nv = *(const float4*)&ns_s[(h * 16 + rr) * 256 + kc * 4];
            acc[rr] += nv.x * w0 + nv.y * w1 + nv.z * w2 + nv.w * w3;
        }
    }
    #pragma unroll
    for (int rr = 0; rr < 16; ++rr) {
        int row = h * 16 + rr;
        if (row < m) center_bf[ids_s[row] * UC + j] = f2bf(acc[rr]);
    }
}

// ---------- qr[n, r*128+u] = center_bf @ BallQ   (MFMA, bf16) ----------
__global__ __launch_bounds__(256)
void k_qr(const unsigned short* __restrict__ center_bf,
          const unsigned short* __restrict__ Bfrag,
          unsigned short* __restrict__ qr) {
    int w = threadIdx.x >> 6, l = threadIdx.x & 63;
    int n0 = blockIdx.x * 128 + w * 32;
    int ct0 = blockIdx.y * 4;                 // 4 col-tiles = 64 cols
    float4v acc[2][4] = {};
    #pragma unroll
    for (int ks = 0; ks < 4; ++ks) {
        short8 a[2], b[4];
        #pragma unroll
        for (int mi = 0; mi < 2; ++mi) {
            int row = n0 + mi * 16 + (l & 15);
            a[mi] = *(const short8*)&center_bf[row * 128 + ks * 32 + ((l >> 4) << 3)];
        }
        #pragma unroll
        for (int ci = 0; ci < 4; ++ci)
            b[ci] = *(const short8*)&Bfrag[(((ks * 64 + ct0 + ci) << 6) + l) * 8];
        #pragma unroll
        for (int mi = 0; mi < 2; ++mi)
            #pragma unroll
            for (int ci = 0; ci < 4; ++ci)
                acc[mi][ci] = __builtin_amdgcn_mfma_f32_16x16x32_bf16(a[mi], b[ci], acc[mi][ci], 0, 0, 0);
    }
    #pragma unroll
    for (int mi = 0; mi < 2; ++mi)
        #pragma unroll
        for (int ci = 0; ci < 4; ++ci)
            #pragma unroll
            for (int reg = 0; reg < 4; ++reg) {
                int row = n0 + mi * 16 + ((l >> 4) << 2) + reg;
                int col = (ct0 + ci) * 16 + (l & 15);
                qr[(size_t)row * 1024 + col] = f2bf(acc[mi][ci][reg]);
            }
}

// ---------- fused: scores + softmax + bucket accumulate ----------
__global__ void k_attbucket(const unsigned short* __restrict__ center_bf,
                            const unsigned short* __restrict__ qr,
                            const int* __restrict__ adj, const int* __restrict__ rel,
                            unsigned short* __restrict__ bucketA) {
    int wv = threadIdx.x >> 6, l = threadIdx.x & 63;
    int d = l & 31, half = l >> 5;
    int nbase = blockIdx.x * 16 + wv * 4;
    for (int q = 0; q < 4; ++q) {
        int n = nbase + q;
        int ai = adj[n * DD + d];
        int rd = rel[n * DD + d];
        int row = ai > 0 ? ai - 1 : 0;
        const unsigned short* xb = center_bf + (size_t)row * 128 + half * 64;
        const unsigned short* qb = qr + (size_t)n * 1024 + rd * 128 + half * 64;
        float s = 0.f;
        #pragma unroll
        for (int k = 0; k < 8; ++k) {
            uint2 xu = *(const uint2*)&xb[k * 8 + 0];
            uint2 qu = *(const uint2*)&qb[k * 8 + 0];
            uint2 xv = *(const uint2*)&xb[k * 8 + 4];
            uint2 qv = *(const uint2*)&qb[k * 8 + 4];
            s += bflo(xu.x) * bflo(qu.x) + bfhi(xu.x) * bfhi(qu.x);
            s += bflo(xu.y) * bflo(qu.y) + bfhi(xu.y) * bfhi(qu.y);
            s += bflo(xv.x) * bflo(qv.x) + bfhi(xv.x) * bfhi(qv.x);
            s += bflo(xv.y) * bflo(qv.y) + bfhi(xv.y) * bfhi(qv.y);
        }
        s += __shfl_xor(s, 32, 64);        // merge halves
        if (ai == 0) s = 0.f;              // zero neighbor row -> score 0
        if (rd == 0) s = -1e9f;            // padded edge mask
        float mx = s;
        #pragma unroll
        for (int off = 16; off > 0; off >>= 1)
            mx = fmaxf(mx, __shfl_xor(mx, off, 64));
        float ex = __expf(s - mx);
        float sm = ex;
        #pragma unroll
        for (int off = 16; off > 0; off >>= 1)
            sm += __shfl_xor(sm, off, 64);
        float a = ex / sm;
        if (ai == 0) a = 0.f;              // pad row contributes exactly 0 to V

        // bucket phase: lane l owns channels 2l, 2l+1; broadcast edge data via shfl
        float bk0[8], bk1[8];
        #pragma unroll
        for (int r = 0; r < 8; ++r) { bk0[r] = 0.f; bk1[r] = 0.f; }
        #pragma unroll 4
        for (int dd = 0; dd < 32; ++dd) {
            float ad = __shfl(a, dd, 64);
            int rv = __shfl(rd, dd, 64);
            int rw = __shfl(row, dd, 64);
            unsigned xu = *(const unsigned*)&center_bf[(size_t)rw * 128 + l * 2];
            float t0 = ad * bflo(xu), t1 = ad * bfhi(xu);
            #pragma unroll
            for (int r = 0; r < 8; ++r) {
                bool m = (rv == r);
                bk0[r] += m ? t0 : 0.f;
                bk1[r] += m ? t1 : 0.f;
            }
        }
        #pragma unroll
        for (int r = 0; r < 8; ++r) {
            unsigned pk = (unsigned)f2bf(bk0[r]) | ((unsigned)f2bf(bk1[r]) << 16);
            *(unsigned*)&bucketA[(size_t)n * 1024 + r * 128 + l * 2] = pk;
        }
    }
}

// ---------- agg = bucketA @ RVB (MFMA) ; out = center + relu(agg@fcw + b) ----------
__global__ __launch_bounds__(256)
void k_out(const unsigned short* __restrict__ Abf, const unsigned short* __restrict__ RVBfrag,
           const float* __restrict__ fcw, const float* __restrict__ fcb,
           const unsigned short* __restrict__ center_bf, float* __restrict__ out) {
    __shared__ float agg_s[16 * 132];   // ~8.25 KB
    int w = threadIdx.x >> 6, l = threadIdx.x & 63;
    int n0 = blockIdx.x * 16;
    float4v acc[2] = {};
    int arow = n0 + (l & 15);
    #pragma unroll 4
    for (int ks = 0; ks < 32; ++ks) {
        short8 a = *(const short8*)&Abf[(size_t)arow * 1024 + ks * 32 + ((l >> 4) << 3)];
        #pragma unroll
        for (int ci = 0; ci < 2; ++ci) {
            short8 b = *(const short8*)&RVBfrag[(((ks * 8 + w * 2 + ci) << 6) + l) * 8];
            acc[ci] = __builtin_amdgcn_mfma_f32_16x16x32_bf16(a, b, acc[ci], 0, 0, 0);
        }
    }
    #pragma unroll
    for (int ci = 0; ci < 2; ++ci)
        #pragma unroll
        for (int reg = 0; reg < 4; ++reg) {
            int row = ((l >> 4) << 2) + reg;
            int col = (w * 2 + ci) * 16 + (l & 15);
            agg_s[row * 132 + col] = acc[ci][reg];
        }
    __syncthreads();

    int j = threadIdx.x & 127, h = threadIdx.x >> 7;
    float acc2[8];
    #pragma unroll
    for (int rr = 0; rr < 8; ++rr) acc2[rr] = 0.f;
    for (int kc = 0; kc < 32; ++kc) {
        float w0 = fcw[(kc * 4 + 0) * 128 + j];
        float w1 = fcw[(kc * 4 + 1) * 128 + j];
        float w2 = fcw[(kc * 4 + 2) * 128 + j];
        float w3 = fcw[(kc * 4 + 3) * 128 + j];
        #pragma unroll
        for (int rr = 0; rr < 8; ++rr) {
            float4 a4 = *(const float4*)&agg_s[(h * 8 + rr) * 132 + kc * 4];
            acc2[rr] += a4.x * w0 + a4.y * w1 + a4.z * w2 + a4.w * w3;
        }
    }
    float b = fcb[j];
    #pragma unroll
    for (int rr = 0; rr < 8; ++rr) {
        int n = n0 + h * 8 + rr;
        float v = acc2[rr] + b;
        v = v > 0.f ? v : 0.f;
        out[(size_t)n * 128 + j] = bf2f(center_bf[(size_t)n * 128 + j]) + v;
    }
}

extern "C" void kernel_launch(void* const* d_in, const int* in_sizes, int n_in,
                              void* d_out, int out_size, void* d_ws, size_t ws_size,
                              hipStream_t stream) {
    const float* node_state = (const float*)d_in[0];
    const int*   adjacency  = (const int*)d_in[1];
    const int*   point_enc  = (const int*)d_in[2];
    const int*   relation   = (const int*)d_in[3];
    const float* pew        = (const float*)d_in[4];
    const float* relw       = (const float*)d_in[5];
    const float* qw         = (const float*)d_in[6];
    const float* kw         = (const float*)d_in[7];
    const float* vw         = (const float*)d_in[8];
    const float* fcw        = (const float*)d_in[9];
    const float* fcb        = (const float*)d_in[10];
    float* out = (float*)d_out;

    char* ws = (char*)d_ws;
    unsigned short* BallQfrag = (unsigned short*)ws;  ws += 128 * 1024 * 2;            // 256 KB
    unsigned short* RVBfrag   = (unsigned short*)ws;  ws += 1024 * 128 * 2;            // 256 KB
    unsigned short* center_bf = (unsigned short*)ws;  ws += (size_t)NNODE * 128 * 2;   // 4 MB
    int* blockhist            = (int*)ws;             ws += 64 * 8 * 4;
    int* blockoff             = (int*)ws;             ws += 64 * 8 * 4;
    int* cnt                  = (int*)ws;             ws += 8 * 4;
    int* basep                = (int*)ws;             ws += 8 * 4;
    int* list                 = (int*)ws;             ws += NNODE * 4;                 // 64 KB
    unsigned short* qr        = (unsigned short*)ws;                                   // 33 MB
    unsigned short* bucketA   = qr;   // overlay: qr dead after k_attbucket reads it

    k_prep<<<dim3(8, 8), 256, 0, stream>>>(qw, kw, relw, vw, BallQfrag, RVBfrag);
    k_hist<<<NNODE / 256, 256, 0, stream>>>(point_enc, blockhist);
    k_scanoff<<<1, 64, 0, stream>>>(blockhist, blockoff, cnt, basep);
    k_scatter<<<NNODE / 256, 256, 0, stream>>>(point_enc, blockoff, list);
    k_center<<<dim3(NNODE / 32, EC), 256, 0, stream>>>(node_state, pew, list, cnt, basep, center_bf);
    k_qr<<<dim3(NNODE / 128, 16), 256, 0, stream>>>(center_bf, BallQfrag, qr);
    k_attbucket<<<NNODE / 16, 256, 0, stream>>>(center_bf, qr, adjacency, relation, bucketA);
    k_out<<<NNODE / 16, 256, 0, stream>>>(bucketA, RVBfrag, fcw, fcb, center_bf, out);
}

// Round 6
// 249.118 us; speedup vs baseline: 4.0517x; 1.1541x over previous
//
#include <hip/hip_runtime.h>

#define NNODE 16384
#define DD 32
#define INPC 256
#define UC 128
#define RC 8
#define EC 8

typedef __attribute__((ext_vector_type(8))) short short8;
typedef __attribute__((ext_vector_type(4))) float float4v;

__device__ __forceinline__ unsigned short f2bf(float f) {
    unsigned u = __builtin_bit_cast(unsigned, f);
    unsigned r = (u + 0x7FFFu + ((u >> 16) & 1u)) >> 16;   // RNE
    return (unsigned short)r;
}
__device__ __forceinline__ float bflo(unsigned u) { return __builtin_bit_cast(float, u << 16); }
__device__ __forceinline__ float bfhi(unsigned u) { return __builtin_bit_cast(float, u & 0xFFFF0000u); }
__device__ __forceinline__ float bf2f(unsigned short s) { return __builtin_bit_cast(float, (unsigned)s << 16); }

// B-fragment flat index for mfma_f32_16x16x32_bf16. nct = #16-col tiles.
__device__ __forceinline__ int bfrag_idx(int k, int col, int nct) {
    int ks = k >> 5, ct = col >> 4;
    int l = (((k >> 3) & 3) << 4) | (col & 15);
    return (((ks * nct + ct) << 6) + l) * 8 + (k & 7);
}

// ---------- conversions: ns -> bf16, pew -> bf16 B-fragments ----------
__global__ void k_conv(const float* __restrict__ ns, const float* __restrict__ pew,
                       unsigned short* __restrict__ ns_bf, unsigned short* __restrict__ pewfrag) {
    int b = blockIdx.x;
    if (b < 4096) {                      // ns: 4096*256*4 = 4194304 elems
        int i = (b * 256 + threadIdx.x) * 4;
        float4 v = *(const float4*)&ns[i];
        uint2 o;
        o.x = (unsigned)f2bf(v.x) | ((unsigned)f2bf(v.y) << 16);
        o.y = (unsigned)f2bf(v.z) | ((unsigned)f2bf(v.w) << 16);
        *(uint2*)&ns_bf[i] = o;
    } else {                             // pew: 1024*256 = 262144 elems
        int id = (b - 4096) * 256 + threadIdx.x;
        int e = id >> 15, k = (id >> 7) & 255, col = id & 127;
        pewfrag[(e << 15) + bfrag_idx(k, col, 8)] = f2bf(pew[id]);
    }
}

// ---------- prep (fused): P rows in LDS, then BallQfrag / RVBfrag ----------
__global__ void k_prep(const float* __restrict__ qw, const float* __restrict__ kw,
                       const float* __restrict__ relw, const float* __restrict__ vw,
                       unsigned short* __restrict__ BallQfrag,
                       unsigned short* __restrict__ RVBfrag) {
    __shared__ float P_s[16 * 128];
    int r = blockIdx.x, i0 = blockIdx.y * 16;
    int j = threadIdx.x & 127, h = threadIdx.x >> 7;
    {
        float acc[8] = {0,0,0,0,0,0,0,0};
        const float4* kr = (const float4*)(kw + j * UC);
        for (int lc = 0; lc < 32; ++lc) {
            float4 b = kr[lc];
            #pragma unroll
            for (int ii = 0; ii < 8; ++ii) {
                float4 a = *(const float4*)&qw[(i0 + h * 8 + ii) * UC + lc * 4];
                acc[ii] += a.x * b.x + a.y * b.y + a.z * b.z + a.w * b.w;
            }
        }
        #pragma unroll
        for (int ii = 0; ii < 8; ++ii)
            P_s[(h * 8 + ii) * 128 + j] = acc[ii] * (1.0f / 128.0f);
    }
    __syncthreads();

    const float* R = relw + r * UC * UC;
    float accM[8] = {0,0,0,0,0,0,0,0};
    for (int mc = 0; mc < 32; ++mc) {
        float4 rv = *(const float4*)&R[j * UC + mc * 4];
        #pragma unroll
        for (int ii = 0; ii < 8; ++ii) {
            float4 p = *(const float4*)&P_s[(h * 8 + ii) * 128 + mc * 4];
            accM[ii] += p.x * rv.x + p.y * rv.y + p.z * rv.z + p.w * rv.w;
        }
    }
    #pragma unroll
    for (int ii = 0; ii < 8; ++ii) {
        int i = i0 + h * 8 + ii;
        BallQfrag[bfrag_idx(i, r * 128 + j, 64)] = f2bf(accM[ii]);
    }

    float accV[8] = {0,0,0,0,0,0,0,0};
    for (int m = 0; m < UC; ++m) {
        float v = vw[m * UC + j];
        #pragma unroll
        for (int ii = 0; ii < 8; ++ii)
            accV[ii] += R[(i0 + h * 8 + ii) * UC + m] * v;
    }
    #pragma unroll
    for (int ii = 0; ii < 8; ++ii) {
        int i = i0 + h * 8 + ii;
        RVBfrag[bfrag_idx(r * 128 + i, j, 8)] = f2bf(accV[ii]);
    }
}

// ---------- compaction (no global atomics) ----------
__global__ void k_hist(const int* __restrict__ pe, int* __restrict__ blockhist) {
    __shared__ int hh[8];
    if (threadIdx.x < 8) hh[threadIdx.x] = 0;
    __syncthreads();
    atomicAdd(&hh[pe[blockIdx.x * 256 + threadIdx.x]], 1);
    __syncthreads();
    if (threadIdx.x < 8) blockhist[blockIdx.x * 8 + threadIdx.x] = hh[threadIdx.x];
}

__global__ void k_scanoff(const int* __restrict__ blockhist, int* __restrict__ blockoff,
                          int* __restrict__ cnt, int* __restrict__ basep) {
    __shared__ int tot[8];
    int e = threadIdx.x;
    if (e < 8) {
        int run = 0;
        for (int b = 0; b < 64; ++b) run += blockhist[b * 8 + e];
        tot[e] = run;
        cnt[e] = run;
    }
    __syncthreads();
    if (e < 8) {
        int base = 0;
        for (int i = 0; i < e; ++i) base += tot[i];
        basep[e] = base;
        int run = base;
        for (int b = 0; b < 64; ++b) { blockoff[b * 8 + e] = run; run += blockhist[b * 8 + e]; }
    }
}

__global__ void k_scatter(const int* __restrict__ pe, const int* __restrict__ blockoff,
                          int* __restrict__ list) {
    __shared__ int wavecnt[4 * 8];
    int t = threadIdx.x, w = t >> 6, l = t & 63;
    int n = blockIdx.x * 256 + t;
    int e = pe[n];
    unsigned long long mymask = 0;
    #pragma unroll
    for (int r = 0; r < 8; ++r) {
        unsigned long long m = __ballot(e == r);
        if (e == r) mymask = m;
        if (l == r) wavecnt[w * 8 + r] = (int)__popcll(m);
    }
    __syncthreads();
    int off = 0;
    for (int w2 = 0; w2 < w; ++w2) off += wavecnt[w2 * 8 + e];
    unsigned long long ltmask = (1ull << l) - 1ull;
    int rank = (int)__popcll(mymask & ltmask);
    list[blockoff[blockIdx.x * 8 + e] + off + rank] = n;
}

// ---------- center (MFMA): center_bf[list-rows] = ns_bf @ pewfrag[e] ----------
__global__ __launch_bounds__(256, 4)
void k_center(const unsigned short* __restrict__ ns_bf, const unsigned short* __restrict__ pewfrag,
              const int* __restrict__ list, const int* __restrict__ cnt,
              const int* __restrict__ base, unsigned short* __restrict__ center_bf) {
    int e = blockIdx.y;
    int c = cnt[e];
    int start = blockIdx.x * 16;
    if (start >= c) return;
    int w = threadIdx.x >> 6, l = threadIdx.x & 63;

    int idx16 = start + (l & 15);
    int rid = list[base[e] + min(idx16, c - 1)];

    float4v acc[2] = {};
    const unsigned short* pf = pewfrag + ((size_t)e << 15);
    #pragma unroll
    for (int ks = 0; ks < 8; ++ks) {
        short8 a = *(const short8*)&ns_bf[(size_t)rid * 256 + ks * 32 + ((l >> 4) << 3)];
        #pragma unroll
        for (int ci = 0; ci < 2; ++ci) {
            int ct = w * 2 + ci;
            short8 b = *(const short8*)&pf[(((ks * 8 + ct) << 6) + l) * 8];
            acc[ci] = __builtin_amdgcn_mfma_f32_16x16x32_bf16(a, b, acc[ci], 0, 0, 0);
        }
    }
    #pragma unroll
    for (int reg = 0; reg < 4; ++reg) {
        int row16 = start + ((l >> 4) << 2) + reg;
        if (row16 < c) {
            int gid = list[base[e] + row16];
            #pragma unroll
            for (int ci = 0; ci < 2; ++ci)
                center_bf[(size_t)gid * 128 + (w * 2 + ci) * 16 + (l & 15)] = f2bf(acc[ci][reg]);
        }
    }
}

// ---------- fused: qr (MFMA->LDS) + scores (MFMA) + softmax + bucket (switch) ----------
#define QSTRIDE 1096   // elems per node row in LDS (16B aligned, bank-spread)
__global__ __launch_bounds__(256, 4)
void k_fused(const unsigned short* __restrict__ center_bf,
             const unsigned short* __restrict__ BallQfrag,
             const int* __restrict__ adj, const int* __restrict__ rel,
             unsigned short* __restrict__ bucketA) {
    __shared__ unsigned short qlds[16 * QSTRIDE];   // ~35 KB
    int w = threadIdx.x >> 6, l = threadIdx.x & 63;
    int n0 = blockIdx.x * 16;

    // phase 1: qr tile (16 nodes x 1024) into LDS. wave w computes cols ct=w*16..+16
    {
        short8 a[4];
        #pragma unroll
        for (int ks = 0; ks < 4; ++ks)
            a[ks] = *(const short8*)&center_bf[(size_t)(n0 + (l & 15)) * 128 + ks * 32 + ((l >> 4) << 3)];
        for (int ci = 0; ci < 16; ++ci) {
            int ct = w * 16 + ci;
            float4v acc = {};
            #pragma unroll
            for (int ks = 0; ks < 4; ++ks) {
                short8 b = *(const short8*)&BallQfrag[(((ks * 64 + ct) << 6) + l) * 8];
                acc = __builtin_amdgcn_mfma_f32_16x16x32_bf16(a[ks], b, acc, 0, 0, 0);
            }
            int r = ct >> 3;
            int ch = (ct & 7) * 16 + (l & 15);
            #pragma unroll
            for (int reg = 0; reg < 4; ++reg) {
                int rn = ((l >> 4) << 2) + reg;
                qlds[rn * QSTRIDE + r * 136 + ch] = f2bf(acc[reg]);
            }
        }
    }
    __syncthreads();

    // phase 2: wave w handles nodes n0 + w*4 .. +4
    for (int q = 0; q < 4; ++q) {
        int tn = w * 4 + q;
        int n = n0 + tn;
        int ai[2], rv[2], rowv[2];
        #pragma unroll
        for (int t = 0; t < 2; ++t) {
            ai[t] = adj[n * DD + t * 16 + (l & 15)];
            rv[t] = rel[n * DD + t * 16 + (l & 15)];
            rowv[t] = ai[t] > 0 ? ai[t] - 1 : 0;
        }
        // scores via MFMA: X(32x128) @ Q^T(128x8->16)
        float4v sc[2] = {};
        #pragma unroll
        for (int ks = 0; ks < 4; ++ks) {
            short8 qb = *(const short8*)&qlds[tn * QSTRIDE + (l & 7) * 136 + ks * 32 + ((l >> 4) << 3)];
            #pragma unroll
            for (int t = 0; t < 2; ++t) {
                short8 xa = *(const short8*)&center_bf[(size_t)rowv[t] * 128 + ks * 32 + ((l >> 4) << 3)];
                sc[t] = __builtin_amdgcn_mfma_f32_16x16x32_bf16(xa, qb, sc[t], 0, 0, 0);
            }
        }
        // select col rd per edge, mask, softmax
        float sel[2][4];
        int ai2[2][4], rd2[2][4];
        #pragma unroll
        for (int t = 0; t < 2; ++t)
            #pragma unroll
            for (int reg = 0; reg < 4; ++reg) {
                int e2l = ((l >> 4) & 3) * 4 + reg;
                rd2[t][reg] = __shfl(rv[t], (l & 48) | e2l, 64);
                ai2[t][reg] = __shfl(ai[t], (l & 48) | e2l, 64);
                float s = __shfl(sc[t][reg], (l & 48) | rd2[t][reg], 64);
                if (ai2[t][reg] == 0) s = 0.f;
                if (rd2[t][reg] == 0) s = -1e9f;
                sel[t][reg] = s;
            }
        float mx = sel[0][0];
        #pragma unroll
        for (int t = 0; t < 2; ++t)
            #pragma unroll
            for (int reg = 0; reg < 4; ++reg) mx = fmaxf(mx, sel[t][reg]);
        mx = fmaxf(mx, __shfl_xor(mx, 16, 64));
        mx = fmaxf(mx, __shfl_xor(mx, 32, 64));
        float at[2][4];
        float sm = 0.f;
        #pragma unroll
        for (int t = 0; t < 2; ++t)
            #pragma unroll
            for (int reg = 0; reg < 4; ++reg) {
                at[t][reg] = __expf(sel[t][reg] - mx);
                sm += at[t][reg];
            }
        sm += __shfl_xor(sm, 16, 64);
        sm += __shfl_xor(sm, 32, 64);
        float inv = 1.0f / sm;
        #pragma unroll
        for (int t = 0; t < 2; ++t)
            #pragma unroll
            for (int reg = 0; reg < 4; ++reg) {
                at[t][reg] *= inv;
                if (ai2[t][reg] == 0) at[t][reg] = 0.f;   // zero V row
            }

        // bucket: per-edge scalar broadcast + switch accumulate (lane owns ch 2l,2l+1)
        float bk0[8], bk1[8];
        #pragma unroll
        for (int r = 0; r < 8; ++r) { bk0[r] = 0.f; bk1[r] = 0.f; }
        #pragma unroll
        for (int t = 0; t < 2; ++t)
            #pragma unroll
            for (int g = 0; g < 4; ++g)
                #pragma unroll
                for (int reg = 0; reg < 4; ++reg) {
                    float ad = __shfl(at[t][reg], g << 4, 64);
                    int rowe = __shfl(rowv[t], g * 4 + reg, 64);
                    int rve = __builtin_amdgcn_readfirstlane(__shfl(rv[t], g * 4 + reg, 64));
                    unsigned xu = *(const unsigned*)&center_bf[(size_t)rowe * 128 + l * 2];
                    float t0 = ad * bflo(xu), t1 = ad * bfhi(xu);
                    switch (rve) {
                        case 0: bk0[0] += t0; bk1[0] += t1; break;
                        case 1: bk0[1] += t0; bk1[1] += t1; break;
                        case 2: bk0[2] += t0; bk1[2] += t1; break;
                        case 3: bk0[3] += t0; bk1[3] += t1; break;
                        case 4: bk0[4] += t0; bk1[4] += t1; break;
                        case 5: bk0[5] += t0; bk1[5] += t1; break;
                        case 6: bk0[6] += t0; bk1[6] += t1; break;
                        case 7: bk0[7] += t0; bk1[7] += t1; break;
                    }
                }
        #pragma unroll
        for (int r = 0; r < 8; ++r) {
            unsigned pk = (unsigned)f2bf(bk0[r]) | ((unsigned)f2bf(bk1[r]) << 16);
            *(unsigned*)&bucketA[(size_t)n * 1024 + r * 128 + l * 2] = pk;
        }
    }
}

// ---------- agg = bucketA @ RVB (MFMA) ; out = center + relu(agg@fcw + b) ----------
__global__ __launch_bounds__(256)
void k_out(const unsigned short* __restrict__ Abf, const unsigned short* __restrict__ RVBfrag,
           const float* __restrict__ fcw, const float* __restrict__ fcb,
           const unsigned short* __restrict__ center_bf, float* __restrict__ out) {
    __shared__ float agg_s[16 * 132];
    int w = threadIdx.x >> 6, l = threadIdx.x & 63;
    int n0 = blockIdx.x * 16;
    float4v acc[2] = {};
    int arow = n0 + (l & 15);
    #pragma unroll 4
    for (int ks = 0; ks < 32; ++ks) {
        short8 a = *(const short8*)&Abf[(size_t)arow * 1024 + ks * 32 + ((l >> 4) << 3)];
        #pragma unroll
        for (int ci = 0; ci < 2; ++ci) {
            short8 b = *(const short8*)&RVBfrag[(((ks * 8 + w * 2 + ci) << 6) + l) * 8];
            acc[ci] = __builtin_amdgcn_mfma_f32_16x16x32_bf16(a, b, acc[ci], 0, 0, 0);
        }
    }
    #pragma unroll
    for (int ci = 0; ci < 2; ++ci)
        #pragma unroll
        for (int reg = 0; reg < 4; ++reg) {
            int row = ((l >> 4) << 2) + reg;
            int col = (w * 2 + ci) * 16 + (l & 15);
            agg_s[row * 132 + col] = acc[ci][reg];
        }
    __syncthreads();

    int j = threadIdx.x & 127, h = threadIdx.x >> 7;
    float acc2[8];
    #pragma unroll
    for (int rr = 0; rr < 8; ++rr) acc2[rr] = 0.f;
    for (int kc = 0; kc < 32; ++kc) {
        float w0 = fcw[(kc * 4 + 0) * 128 + j];
        float w1 = fcw[(kc * 4 + 1) * 128 + j];
        float w2 = fcw[(kc * 4 + 2) * 128 + j];
        float w3 = fcw[(kc * 4 + 3) * 128 + j];
        #pragma unroll
        for (int rr = 0; rr < 8; ++rr) {
            float4 a4 = *(const float4*)&agg_s[(h * 8 + rr) * 132 + kc * 4];
            acc2[rr] += a4.x * w0 + a4.y * w1 + a4.z * w2 + a4.w * w3;
        }
    }
    float b = fcb[j];
    #pragma unroll
    for (int rr = 0; rr < 8; ++rr) {
        int n = n0 + h * 8 + rr;
        float v = acc2[rr] + b;
        v = v > 0.f ? v : 0.f;
        out[(size_t)n * 128 + j] = bf2f(center_bf[(size_t)n * 128 + j]) + v;
    }
}

extern "C" void kernel_launch(void* const* d_in, const int* in_sizes, int n_in,
                              void* d_out, int out_size, void* d_ws, size_t ws_size,
                              hipStream_t stream) {
    const float* node_state = (const float*)d_in[0];
    const int*   adjacency  = (const int*)d_in[1];
    const int*   point_enc  = (const int*)d_in[2];
    const int*   relation   = (const int*)d_in[3];
    const float* pew        = (const float*)d_in[4];
    const float* relw       = (const float*)d_in[5];
    const float* qw         = (const float*)d_in[6];
    const float* kw         = (const float*)d_in[7];
    const float* vw         = (const float*)d_in[8];
    const float* fcw        = (const float*)d_in[9];
    const float* fcb        = (const float*)d_in[10];
    float* out = (float*)d_out;

    char* ws = (char*)d_ws;
    unsigned short* BallQfrag = (unsigned short*)ws;  ws += 128 * 1024 * 2;            // 256 KB
    unsigned short* RVBfrag   = (unsigned short*)ws;  ws += 1024 * 128 * 2;            // 256 KB
    unsigned short* center_bf = (unsigned short*)ws;  ws += (size_t)NNODE * 128 * 2;   // 4 MB
    unsigned short* ns_bf     = (unsigned short*)ws;  ws += (size_t)NNODE * 256 * 2;   // 8 MB
    unsigned short* pewfrag   = (unsigned short*)ws;  ws += 8 * 32768 * 2;             // 512 KB
    int* blockhist            = (int*)ws;             ws += 64 * 8 * 4;
    int* blockoff             = (int*)ws;             ws += 64 * 8 * 4;
    int* cnt                  = (int*)ws;             ws += 32;
    int* basep                = (int*)ws;             ws += 32;
    int* list                 = (int*)ws;             ws += NNODE * 4;                 // 64 KB
    unsigned short* bucketA   = (unsigned short*)ws;                                   // 33.5 MB

    k_conv<<<4096 + 1024, 256, 0, stream>>>(node_state, pew, ns_bf, pewfrag);
    k_prep<<<dim3(8, 8), 256, 0, stream>>>(qw, kw, relw, vw, BallQfrag, RVBfrag);
    k_hist<<<NNODE / 256, 256, 0, stream>>>(point_enc, blockhist);
    k_scanoff<<<1, 64, 0, stream>>>(blockhist, blockoff, cnt, basep);
    k_scatter<<<NNODE / 256, 256, 0, stream>>>(point_enc, blockoff, list);
    k_center<<<dim3(192, 8), 256, 0, stream>>>(ns_bf, pewfrag, list, cnt, basep, center_bf);
    k_fused<<<NNODE / 16, 256, 0, stream>>>(center_bf, BallQfrag, adjacency, relation, bucketA);
    k_out<<<NNODE / 16, 256, 0, stream>>>(bucketA, RVBfrag, fcw, fcb, center_bf, out);
}

// Round 7
// 241.233 us; speedup vs baseline: 4.1841x; 1.0327x over previous
//
#include <hip/hip_runtime.h>

#define NNODE 16384
#define DD 32
#define INPC 256
#define UC 128
#define RC 8
#define EC 8

typedef __attribute__((ext_vector_type(8))) short short8;
typedef __attribute__((ext_vector_type(4))) float float4v;

__device__ __forceinline__ unsigned short f2bf(float f) {
    unsigned u = __builtin_bit_cast(unsigned, f);
    unsigned r = (u + 0x7FFFu + ((u >> 16) & 1u)) >> 16;   // RNE
    return (unsigned short)r;
}
__device__ __forceinline__ float bflo(unsigned u) { return __builtin_bit_cast(float, u << 16); }
__device__ __forceinline__ float bfhi(unsigned u) { return __builtin_bit_cast(float, u & 0xFFFF0000u); }
__device__ __forceinline__ float bf2f(unsigned short s) { return __builtin_bit_cast(float, (unsigned)s << 16); }

// B-fragment flat index for mfma_f32_16x16x32_bf16. nct = #16-col tiles.
__device__ __forceinline__ int bfrag_idx(int k, int col, int nct) {
    int ks = k >> 5, ct = col >> 4;
    int l = (((k >> 3) & 3) << 4) | (col & 15);
    return (((ks * nct + ct) << 6) + l) * 8 + (k & 7);
}

// ---------- setup mega-kernel: [0,4096) ns->bf16 | [4096,5120) pew->frag |
//            [5120,5184) prep (P, BallQ, RVF=RV@fcw) | [5184,5248) hist ----------
__global__ void k_setup(const float* __restrict__ ns, const float* __restrict__ pew,
                        const float* __restrict__ qw, const float* __restrict__ kw,
                        const float* __restrict__ relw, const float* __restrict__ vw,
                        const float* __restrict__ fcw, const int* __restrict__ pe,
                        unsigned short* __restrict__ ns_bf, unsigned short* __restrict__ pewfrag,
                        unsigned short* __restrict__ BallQfrag, unsigned short* __restrict__ RVFfrag,
                        int* __restrict__ blockhist) {
    __shared__ float P_s[16 * 128];   // 8 KB (prep blocks)
    __shared__ int hh[8];             // hist blocks
    int b = blockIdx.x;
    if (b < 4096) {                   // ns conversion
        int i = (b * 256 + threadIdx.x) * 4;
        float4 v = *(const float4*)&ns[i];
        uint2 o;
        o.x = (unsigned)f2bf(v.x) | ((unsigned)f2bf(v.y) << 16);
        o.y = (unsigned)f2bf(v.z) | ((unsigned)f2bf(v.w) << 16);
        *(uint2*)&ns_bf[i] = o;
        return;
    }
    if (b < 5120) {                   // pew -> B-fragments
        int id = (b - 4096) * 256 + threadIdx.x;
        int e = id >> 15, k = (id >> 7) & 255, col = id & 127;
        pewfrag[(e << 15) + bfrag_idx(k, col, 8)] = f2bf(pew[id]);
        return;
    }
    if (b < 5184) {                   // prep
        int pb = b - 5120;
        int r = pb & 7, i0 = (pb >> 3) * 16;
        int j = threadIdx.x & 127, h = threadIdx.x >> 7;
        {   // P rows i0..i0+16 (q_w @ k_w^T)/128
            float acc[8] = {0,0,0,0,0,0,0,0};
            const float4* kr = (const float4*)(kw + j * UC);
            for (int lc = 0; lc < 32; ++lc) {
                float4 bb = kr[lc];
                #pragma unroll
                for (int ii = 0; ii < 8; ++ii) {
                    float4 a = *(const float4*)&qw[(i0 + h * 8 + ii) * UC + lc * 4];
                    acc[ii] += a.x * bb.x + a.y * bb.y + a.z * bb.z + a.w * bb.w;
                }
            }
            #pragma unroll
            for (int ii = 0; ii < 8; ++ii)
                P_s[(h * 8 + ii) * 128 + j] = acc[ii] * (1.0f / 128.0f);
        }
        __syncthreads();

        const float* R = relw + r * UC * UC;
        float accM[8] = {0,0,0,0,0,0,0,0};
        for (int mc = 0; mc < 32; ++mc) {
            float4 rv = *(const float4*)&R[j * UC + mc * 4];
            #pragma unroll
            for (int ii = 0; ii < 8; ++ii) {
                float4 p = *(const float4*)&P_s[(h * 8 + ii) * 128 + mc * 4];
                accM[ii] += p.x * rv.x + p.y * rv.y + p.z * rv.z + p.w * rv.w;
            }
        }
        #pragma unroll
        for (int ii = 0; ii < 8; ++ii)
            BallQfrag[bfrag_idx(i0 + h * 8 + ii, r * 128 + j, 64)] = f2bf(accM[ii]);

        // RV rows = rel_w[r] @ v_w (rows i0..+16)
        float accV[8] = {0,0,0,0,0,0,0,0};
        for (int m = 0; m < UC; ++m) {
            float v = vw[m * UC + j];
            #pragma unroll
            for (int ii = 0; ii < 8; ++ii)
                accV[ii] += R[(i0 + h * 8 + ii) * UC + m] * v;
        }
        __syncthreads();   // P_s dead, reuse for RV rows
        #pragma unroll
        for (int ii = 0; ii < 8; ++ii)
            P_s[(h * 8 + ii) * 128 + j] = accV[ii];
        __syncthreads();

        // RVF rows = RV rows @ fc_w
        float accF[8] = {0,0,0,0,0,0,0,0};
        for (int m = 0; m < UC; ++m) {
            float w = fcw[m * UC + j];
            #pragma unroll
            for (int ii = 0; ii < 8; ++ii)
                accF[ii] += P_s[(h * 8 + ii) * 128 + m] * w;
        }
        #pragma unroll
        for (int ii = 0; ii < 8; ++ii)
            RVFfrag[bfrag_idx(i0 + h * 8 + ii, r * 128 + j, 64)] = f2bf(accF[ii]);
        return;
    }
    {   // hist
        int hb = b - 5184;
        if (threadIdx.x < 8) hh[threadIdx.x] = 0;
        __syncthreads();
        atomicAdd(&hh[pe[hb * 256 + threadIdx.x]], 1);
        __syncthreads();
        if (threadIdx.x < 8) blockhist[hb * 8 + threadIdx.x] = hh[threadIdx.x];
    }
}

// ---------- scatter with inline redundant scan (no global atomics) ----------
__global__ void k_scatter(const int* __restrict__ pe, const int* __restrict__ blockhist,
                          int* __restrict__ list, int* __restrict__ cnt, int* __restrict__ basep) {
    __shared__ int boff[8];
    __shared__ int wavecnt[4 * 8];
    int t = threadIdx.x;
    if (t < 8) {
        int e = t;
        int tote[8];
        #pragma unroll
        for (int e2 = 0; e2 < 8; ++e2) {
            int s = 0;
            for (int bb = 0; bb < 64; ++bb) s += blockhist[bb * 8 + e2];
            tote[e2] = s;
        }
        int base = 0;
        for (int e2 = 0; e2 < 8; ++e2) if (e2 < e) base += tote[e2];
        int off = base;
        for (int bb = 0; bb < (int)blockIdx.x; ++bb) off += blockhist[bb * 8 + e];
        boff[e] = off;
        if (blockIdx.x == 0) { cnt[e] = tote[e]; basep[e] = base; }
    }
    __syncthreads();
    int w = t >> 6, l = t & 63;
    int n = blockIdx.x * 256 + t;
    int e = pe[n];
    unsigned long long mymask = 0;
    #pragma unroll
    for (int r = 0; r < 8; ++r) {
        unsigned long long m = __ballot(e == r);
        if (e == r) mymask = m;
        if (l == r) wavecnt[w * 8 + r] = (int)__popcll(m);
    }
    __syncthreads();
    int off = 0;
    for (int w2 = 0; w2 < w; ++w2) off += wavecnt[w2 * 8 + e];
    unsigned long long ltmask = (1ull << l) - 1ull;
    int rank = (int)__popcll(mymask & ltmask);
    list[boff[e] + off + rank] = n;
}

// ---------- center (MFMA): center_bf[list-rows] = ns_bf @ pewfrag[e] ----------
__global__ __launch_bounds__(256, 4)
void k_center(const unsigned short* __restrict__ ns_bf, const unsigned short* __restrict__ pewfrag,
              const int* __restrict__ list, const int* __restrict__ cnt,
              const int* __restrict__ base, unsigned short* __restrict__ center_bf) {
    int e = blockIdx.y;
    int c = cnt[e];
    int start = blockIdx.x * 16;
    if (start >= c) return;
    int w = threadIdx.x >> 6, l = threadIdx.x & 63;

    int idx16 = start + (l & 15);
    int rid = list[base[e] + min(idx16, c - 1)];

    float4v acc[2] = {};
    const unsigned short* pf = pewfrag + ((size_t)e << 15);
    #pragma unroll
    for (int ks = 0; ks < 8; ++ks) {
        short8 a = *(const short8*)&ns_bf[(size_t)rid * 256 + ks * 32 + ((l >> 4) << 3)];
        #pragma unroll
        for (int ci = 0; ci < 2; ++ci) {
            int ct = w * 2 + ci;
            short8 b = *(const short8*)&pf[(((ks * 8 + ct) << 6) + l) * 8];
            acc[ci] = __builtin_amdgcn_mfma_f32_16x16x32_bf16(a, b, acc[ci], 0, 0, 0);
        }
    }
    #pragma unroll
    for (int reg = 0; reg < 4; ++reg) {
        int row16 = start + ((l >> 4) << 2) + reg;
        if (row16 < c) {
            int gid = list[base[e] + row16];
            #pragma unroll
            for (int ci = 0; ci < 2; ++ci)
                center_bf[(size_t)gid * 128 + (w * 2 + ci) * 16 + (l & 15)] = f2bf(acc[ci][reg]);
        }
    }
}

// ---------- CW = center @ RVFall  (MFMA, bf16 out, row-major [n][r*128+c]) ----------
__global__ __launch_bounds__(256)
void k_qcw(const unsigned short* __restrict__ center_bf,
           const unsigned short* __restrict__ Bfrag,
           unsigned short* __restrict__ CW) {
    int w = threadIdx.x >> 6, l = threadIdx.x & 63;
    int n0 = blockIdx.x * 128 + w * 32;
    int ct0 = blockIdx.y * 4;
    float4v acc[2][4] = {};
    #pragma unroll
    for (int ks = 0; ks < 4; ++ks) {
        short8 a[2], b[4];
        #pragma unroll
        for (int mi = 0; mi < 2; ++mi) {
            int row = n0 + mi * 16 + (l & 15);
            a[mi] = *(const short8*)&center_bf[row * 128 + ks * 32 + ((l >> 4) << 3)];
        }
        #pragma unroll
        for (int ci = 0; ci < 4; ++ci)
            b[ci] = *(const short8*)&Bfrag[(((ks * 64 + ct0 + ci) << 6) + l) * 8];
        #pragma unroll
        for (int mi = 0; mi < 2; ++mi)
            #pragma unroll
            for (int ci = 0; ci < 4; ++ci)
                acc[mi][ci] = __builtin_amdgcn_mfma_f32_16x16x32_bf16(a[mi], b[ci], acc[mi][ci], 0, 0, 0);
    }
    #pragma unroll
    for (int mi = 0; mi < 2; ++mi)
        #pragma unroll
        for (int ci = 0; ci < 4; ++ci)
            #pragma unroll
            for (int reg = 0; reg < 4; ++reg) {
                int row = n0 + mi * 16 + ((l >> 4) << 2) + reg;
                int col = (ct0 + ci) * 16 + (l & 15);
                CW[(size_t)row * 1024 + col] = f2bf(acc[mi][ci][reg]);
            }
}

// ---------- final: qr (MFMA->LDS) + scores (MFMA) + softmax + CW gather + out ----------
#define QSTRIDE 1096
__global__ __launch_bounds__(256, 4)
void k_final(const unsigned short* __restrict__ center_bf,
             const unsigned short* __restrict__ BallQfrag,
             const int* __restrict__ adj, const int* __restrict__ rel,
             const unsigned short* __restrict__ CW,
             const float* __restrict__ fcb, float* __restrict__ out) {
    __shared__ unsigned short qlds[16 * QSTRIDE];   // ~35 KB
    int w = threadIdx.x >> 6, l = threadIdx.x & 63;
    int n0 = blockIdx.x * 16;

    // phase 1: qr tile (16 nodes x 1024) into LDS; wave w computes cols w*256..+256
    {
        short8 a[4];
        #pragma unroll
        for (int ks = 0; ks < 4; ++ks)
            a[ks] = *(const short8*)&center_bf[(size_t)(n0 + (l & 15)) * 128 + ks * 32 + ((l >> 4) << 3)];
        for (int ci = 0; ci < 16; ++ci) {
            int ct = w * 16 + ci;
            float4v acc = {};
            #pragma unroll
            for (int ks = 0; ks < 4; ++ks) {
                short8 b = *(const short8*)&BallQfrag[(((ks * 64 + ct) << 6) + l) * 8];
                acc = __builtin_amdgcn_mfma_f32_16x16x32_bf16(a[ks], b, acc, 0, 0, 0);
            }
            int r = ct >> 3;
            int ch = (ct & 7) * 16 + (l & 15);
            #pragma unroll
            for (int reg = 0; reg < 4; ++reg) {
                int rn = ((l >> 4) << 2) + reg;
                qlds[rn * QSTRIDE + r * 136 + ch] = f2bf(acc[reg]);
            }
        }
    }
    __syncthreads();

    // phase 2: wave w handles nodes n0 + w*4 .. +4
    for (int q = 0; q < 4; ++q) {
        int tn = w * 4 + q;
        int n = n0 + tn;
        int ai[2], rv[2], rowv[2];
        #pragma unroll
        for (int t = 0; t < 2; ++t) {
            ai[t] = adj[n * DD + t * 16 + (l & 15)];
            rv[t] = rel[n * DD + t * 16 + (l & 15)];
            rowv[t] = ai[t] > 0 ? ai[t] - 1 : 0;
        }
        // scores via MFMA: X(16 edges x 128) @ Q^T
        float4v sc[2] = {};
        #pragma unroll
        for (int ks = 0; ks < 4; ++ks) {
            short8 qb = *(const short8*)&qlds[tn * QSTRIDE + (l & 7) * 136 + ks * 32 + ((l >> 4) << 3)];
            #pragma unroll
            for (int t = 0; t < 2; ++t) {
                short8 xa = *(const short8*)&center_bf[(size_t)rowv[t] * 128 + ks * 32 + ((l >> 4) << 3)];
                sc[t] = __builtin_amdgcn_mfma_f32_16x16x32_bf16(xa, qb, sc[t], 0, 0, 0);
            }
        }
        // select col rd per edge, mask, softmax
        float sel[2][4];
        int ai2[2][4], rd2[2][4];
        #pragma unroll
        for (int t = 0; t < 2; ++t)
            #pragma unroll
            for (int reg = 0; reg < 4; ++reg) {
                int e2l = ((l >> 4) & 3) * 4 + reg;
                rd2[t][reg] = __shfl(rv[t], (l & 48) | e2l, 64);
                ai2[t][reg] = __shfl(ai[t], (l & 48) | e2l, 64);
                float s = __shfl(sc[t][reg], (l & 48) | rd2[t][reg], 64);
                if (ai2[t][reg] == 0) s = 0.f;
                if (rd2[t][reg] == 0) s = -1e9f;
                sel[t][reg] = s;
            }
        float mx = sel[0][0];
        #pragma unroll
        for (int t = 0; t < 2; ++t)
            #pragma unroll
            for (int reg = 0; reg < 4; ++reg) mx = fmaxf(mx, sel[t][reg]);
        mx = fmaxf(mx, __shfl_xor(mx, 16, 64));
        mx = fmaxf(mx, __shfl_xor(mx, 32, 64));
        float at[2][4];
        float sm = 0.f;
        #pragma unroll
        for (int t = 0; t < 2; ++t)
            #pragma unroll
            for (int reg = 0; reg < 4; ++reg) {
                at[t][reg] = __expf(sel[t][reg] - mx);
                sm += at[t][reg];
            }
        sm += __shfl_xor(sm, 16, 64);
        sm += __shfl_xor(sm, 32, 64);
        float inv = 1.0f / sm;
        #pragma unroll
        for (int t = 0; t < 2; ++t)
            #pragma unroll
            for (int reg = 0; reg < 4; ++reg) {
                at[t][reg] *= inv;
                if (ai2[t][reg] == 0) at[t][reg] = 0.f;   // zero V row
            }

        // gather-sum of CW rows: out_pre[c] = sum_d attn_d * CW[rowv[d]][rd[d]*128 + c]
        float o0 = 0.f, o1 = 0.f;
        #pragma unroll
        for (int t = 0; t < 2; ++t)
            #pragma unroll
            for (int g = 0; g < 4; ++g)
                #pragma unroll
                for (int reg = 0; reg < 4; ++reg) {
                    float ad = __shfl(at[t][reg], g << 4, 64);
                    int rowe = __builtin_amdgcn_readfirstlane(__shfl(rowv[t], g * 4 + reg, 64));
                    int rve  = __builtin_amdgcn_readfirstlane(__shfl(rv[t],  g * 4 + reg, 64));
                    unsigned cw = *(const unsigned*)&CW[((size_t)rowe * 8 + rve) * 128 + l * 2];
                    o0 += ad * bflo(cw);
                    o1 += ad * bfhi(cw);
                }

        // epilogue: + bias, relu, + center residual
        float2 bb = *(const float2*)&fcb[l * 2];
        unsigned cu = *(const unsigned*)&center_bf[(size_t)n * 128 + l * 2];
        float v0 = o0 + bb.x; v0 = v0 > 0.f ? v0 : 0.f;
        float v1 = o1 + bb.y; v1 = v1 > 0.f ? v1 : 0.f;
        float2 ov;
        ov.x = bflo(cu) + v0;
        ov.y = bfhi(cu) + v1;
        *(float2*)&out[(size_t)n * 128 + l * 2] = ov;
    }
}

extern "C" void kernel_launch(void* const* d_in, const int* in_sizes, int n_in,
                              void* d_out, int out_size, void* d_ws, size_t ws_size,
                              hipStream_t stream) {
    const float* node_state = (const float*)d_in[0];
    const int*   adjacency  = (const int*)d_in[1];
    const int*   point_enc  = (const int*)d_in[2];
    const int*   relation   = (const int*)d_in[3];
    const float* pew        = (const float*)d_in[4];
    const float* relw       = (const float*)d_in[5];
    const float* qw         = (const float*)d_in[6];
    const float* kw         = (const float*)d_in[7];
    const float* vw         = (const float*)d_in[8];
    const float* fcw        = (const float*)d_in[9];
    const float* fcb        = (const float*)d_in[10];
    float* out = (float*)d_out;

    char* ws = (char*)d_ws;
    unsigned short* BallQfrag = (unsigned short*)ws;  ws += 128 * 1024 * 2;            // 256 KB
    unsigned short* RVFfrag   = (unsigned short*)ws;  ws += 128 * 1024 * 2;            // 256 KB
    unsigned short* center_bf = (unsigned short*)ws;  ws += (size_t)NNODE * 128 * 2;   // 4 MB
    unsigned short* ns_bf     = (unsigned short*)ws;  ws += (size_t)NNODE * 256 * 2;   // 8 MB
    unsigned short* pewfrag   = (unsigned short*)ws;  ws += 8 * 32768 * 2;             // 512 KB
    int* blockhist            = (int*)ws;             ws += 64 * 8 * 4;
    int* cnt                  = (int*)ws;             ws += 32;
    int* basep                = (int*)ws;             ws += 32;
    int* list                 = (int*)ws;             ws += NNODE * 4;                 // 64 KB
    unsigned short* CW        = (unsigned short*)ws;                                   // 33.5 MB

    k_setup<<<5248, 256, 0, stream>>>(node_state, pew, qw, kw, relw, vw, fcw, point_enc,
                                      ns_bf, pewfrag, BallQfrag, RVFfrag, blockhist);
    k_scatter<<<64, 256, 0, stream>>>(point_enc, blockhist, list, cnt, basep);
    k_center<<<dim3(192, 8), 256, 0, stream>>>(ns_bf, pewfrag, list, cnt, basep, center_bf);
    k_qcw<<<dim3(128, 16), 256, 0, stream>>>(center_bf, RVFfrag, CW);
    k_final<<<NNODE / 16, 256, 0, stream>>>(center_bf, BallQfrag, adjacency, relation, CW, fcb, out);
}

// Round 8
// 226.572 us; speedup vs baseline: 4.4549x; 1.0647x over previous
//
#include <hip/hip_runtime.h>

#define NNODE 16384
#define DD 32
#define INPC 256
#define UC 128
#define RC 8
#define EC 8

typedef __attribute__((ext_vector_type(8))) short short8;
typedef __attribute__((ext_vector_type(4))) float float4v;

__device__ __forceinline__ unsigned short f2bf(float f) {
    unsigned u = __builtin_bit_cast(unsigned, f);
    unsigned r = (u + 0x7FFFu + ((u >> 16) & 1u)) >> 16;   // RNE
    return (unsigned short)r;
}
__device__ __forceinline__ float bflo(unsigned u) { return __builtin_bit_cast(float, u << 16); }
__device__ __forceinline__ float bfhi(unsigned u) { return __builtin_bit_cast(float, u & 0xFFFF0000u); }
__device__ __forceinline__ float bf2f(unsigned short s) { return __builtin_bit_cast(float, (unsigned)s << 16); }

// B-fragment flat index for mfma_f32_16x16x32_bf16. nct = #16-col tiles.
__device__ __forceinline__ int bfrag_idx(int k, int col, int nct) {
    int ks = k >> 5, ct = col >> 4;
    int l = (((k >> 3) & 3) << 4) | (col & 15);
    return (((ks * nct + ct) << 6) + l) * 8 + (k & 7);
}

// ---------- setup: [0,1024) pew->frag | [1024,1088) prep | [1088,1152) hist ----------
__global__ void k_setup(const float* __restrict__ pew, const float* __restrict__ qw,
                        const float* __restrict__ kw, const float* __restrict__ relw,
                        const float* __restrict__ vw, const float* __restrict__ fcw,
                        const int* __restrict__ pe,
                        unsigned short* __restrict__ pewfrag,
                        unsigned short* __restrict__ BallQfrag, unsigned short* __restrict__ RVFfrag,
                        int* __restrict__ blockhist) {
    __shared__ float P_s[16 * 128];
    __shared__ int hh[8];
    int b = blockIdx.x;
    if (b < 1024) {                   // pew -> B-fragments (K=256, N=128 per entity)
        int id = b * 256 + threadIdx.x;
        int e = id >> 15, k = (id >> 7) & 255, col = id & 127;
        pewfrag[(e << 15) + bfrag_idx(k, col, 8)] = f2bf(pew[id]);
        return;
    }
    if (b < 1088) {                   // prep
        int pb = b - 1024;
        int r = pb & 7, i0 = (pb >> 3) * 16;
        int j = threadIdx.x & 127, h = threadIdx.x >> 7;
        {   // P rows i0..i0+16 = (q_w @ k_w^T)/128
            float acc[8] = {0,0,0,0,0,0,0,0};
            const float4* kr = (const float4*)(kw + j * UC);
            for (int lc = 0; lc < 32; ++lc) {
                float4 bb = kr[lc];
                #pragma unroll
                for (int ii = 0; ii < 8; ++ii) {
                    float4 a = *(const float4*)&qw[(i0 + h * 8 + ii) * UC + lc * 4];
                    acc[ii] += a.x * bb.x + a.y * bb.y + a.z * bb.z + a.w * bb.w;
                }
            }
            #pragma unroll
            for (int ii = 0; ii < 8; ++ii)
                P_s[(h * 8 + ii) * 128 + j] = acc[ii] * (1.0f / 128.0f);
        }
        __syncthreads();

        const float* R = relw + r * UC * UC;
        float accM[8] = {0,0,0,0,0,0,0,0};
        for (int mc = 0; mc < 32; ++mc) {
            float4 rv = *(const float4*)&R[j * UC + mc * 4];
            #pragma unroll
            for (int ii = 0; ii < 8; ++ii) {
                float4 p = *(const float4*)&P_s[(h * 8 + ii) * 128 + mc * 4];
                accM[ii] += p.x * rv.x + p.y * rv.y + p.z * rv.z + p.w * rv.w;
            }
        }
        #pragma unroll
        for (int ii = 0; ii < 8; ++ii)
            BallQfrag[bfrag_idx(i0 + h * 8 + ii, r * 128 + j, 64)] = f2bf(accM[ii]);

        // RV rows = rel_w[r] @ v_w (rows i0..+16)
        float accV[8] = {0,0,0,0,0,0,0,0};
        for (int m = 0; m < UC; ++m) {
            float v = vw[m * UC + j];
            #pragma unroll
            for (int ii = 0; ii < 8; ++ii)
                accV[ii] += R[(i0 + h * 8 + ii) * UC + m] * v;
        }
        __syncthreads();   // P_s dead, reuse for RV rows
        #pragma unroll
        for (int ii = 0; ii < 8; ++ii)
            P_s[(h * 8 + ii) * 128 + j] = accV[ii];
        __syncthreads();

        // RVF rows = RV rows @ fc_w; stored as B-frag with K=1024 (k=r*128+i), N=128
        float accF[8] = {0,0,0,0,0,0,0,0};
        for (int m = 0; m < UC; ++m) {
            float w = fcw[m * UC + j];
            #pragma unroll
            for (int ii = 0; ii < 8; ++ii)
                accF[ii] += P_s[(h * 8 + ii) * 128 + m] * w;
        }
        #pragma unroll
        for (int ii = 0; ii < 8; ++ii)
            RVFfrag[bfrag_idx(r * 128 + i0 + h * 8 + ii, j, 8)] = f2bf(accF[ii]);
        return;
    }
    {   // hist
        int hb = b - 1088;
        if (threadIdx.x < 8) hh[threadIdx.x] = 0;
        __syncthreads();
        atomicAdd(&hh[pe[hb * 256 + threadIdx.x]], 1);
        __syncthreads();
        if (threadIdx.x < 8) blockhist[hb * 8 + threadIdx.x] = hh[threadIdx.x];
    }
}

// ---------- scatter with inline redundant scan (no global atomics) ----------
__global__ void k_scatter(const int* __restrict__ pe, const int* __restrict__ blockhist,
                          int* __restrict__ list, int* __restrict__ cnt, int* __restrict__ basep) {
    __shared__ int boff[8];
    __shared__ int wavecnt[4 * 8];
    int t = threadIdx.x;
    if (t < 8) {
        int e = t;
        int tote[8];
        #pragma unroll
        for (int e2 = 0; e2 < 8; ++e2) {
            int s = 0;
            for (int bb = 0; bb < 64; ++bb) s += blockhist[bb * 8 + e2];
            tote[e2] = s;
        }
        int base = 0;
        for (int e2 = 0; e2 < 8; ++e2) if (e2 < e) base += tote[e2];
        int off = base;
        for (int bb = 0; bb < (int)blockIdx.x; ++bb) off += blockhist[bb * 8 + e];
        boff[e] = off;
        if (blockIdx.x == 0) { cnt[e] = tote[e]; basep[e] = base; }
    }
    __syncthreads();
    int w = t >> 6, l = t & 63;
    int n = blockIdx.x * 256 + t;
    int e = pe[n];
    unsigned long long mymask = 0;
    #pragma unroll
    for (int r = 0; r < 8; ++r) {
        unsigned long long m = __ballot(e == r);
        if (e == r) mymask = m;
        if (l == r) wavecnt[w * 8 + r] = (int)__popcll(m);
    }
    __syncthreads();
    int off = 0;
    for (int w2 = 0; w2 < w; ++w2) off += wavecnt[w2 * 8 + e];
    unsigned long long ltmask = (1ull << l) - 1ull;
    int rank = (int)__popcll(mymask & ltmask);
    list[boff[e] + off + rank] = n;
}

// ---------- center (MFMA): reads fp32 ns directly, converts in-register ----------
__global__ __launch_bounds__(256, 4)
void k_center(const float* __restrict__ ns, const unsigned short* __restrict__ pewfrag,
              const int* __restrict__ list, const int* __restrict__ cnt,
              const int* __restrict__ base, unsigned short* __restrict__ center_bf) {
    int e = blockIdx.y;
    int c = cnt[e];
    int start = blockIdx.x * 16;
    if (start >= c) return;
    int w = threadIdx.x >> 6, l = threadIdx.x & 63;

    int rid = list[base[e] + min(start + (l & 15), c - 1)];

    float4v acc[2] = {};
    const unsigned short* pf = pewfrag + ((size_t)e << 15);
    #pragma unroll
    for (int ks = 0; ks < 8; ++ks) {
        const float* ap = &ns[(size_t)rid * 256 + ks * 32 + ((l >> 4) << 3)];
        float4 v0 = *(const float4*)ap;
        float4 v1 = *(const float4*)(ap + 4);
        short8 a;
        a[0] = f2bf(v0.x); a[1] = f2bf(v0.y); a[2] = f2bf(v0.z); a[3] = f2bf(v0.w);
        a[4] = f2bf(v1.x); a[5] = f2bf(v1.y); a[6] = f2bf(v1.z); a[7] = f2bf(v1.w);
        #pragma unroll
        for (int ci = 0; ci < 2; ++ci) {
            int ct = w * 2 + ci;
            short8 b = *(const short8*)&pf[(((ks * 8 + ct) << 6) + l) * 8];
            acc[ci] = __builtin_amdgcn_mfma_f32_16x16x32_bf16(a, b, acc[ci], 0, 0, 0);
        }
    }
    #pragma unroll
    for (int reg = 0; reg < 4; ++reg) {
        int row16 = start + ((l >> 4) << 2) + reg;
        if (row16 < c) {
            int gid = list[base[e] + row16];
            #pragma unroll
            for (int ci = 0; ci < 2; ++ci)
                center_bf[(size_t)gid * 128 + (w * 2 + ci) * 16 + (l & 15)] = f2bf(acc[ci][reg]);
        }
    }
}

// ---------- final: qr MFMA->LDS + scores MFMA + softmax + reg-bucket ->
//            LDS (overlaying dead qr rows) + bucket@RVF MFMA + epilogue ----------
#define QSTRIDE 1096   // elems/row; 2192 B (16B-mult); dword-stride 548 % 32 = 4 -> 2-way max
__global__ __launch_bounds__(256, 4)
void k_final(const unsigned short* __restrict__ center_bf,
             const unsigned short* __restrict__ BallQfrag,
             const unsigned short* __restrict__ RVFfrag,
             const int* __restrict__ adj, const int* __restrict__ rel,
             const float* __restrict__ fcb, float* __restrict__ out) {
    __shared__ unsigned short qlds[16 * QSTRIDE];   // ~35 KB
    int w = threadIdx.x >> 6, l = threadIdx.x & 63;
    int n0 = blockIdx.x * 16;

    // phase A: qr tile (16 nodes x 1024) into LDS; wave w computes cols w*256..+256
    {
        short8 a[4];
        #pragma unroll
        for (int ks = 0; ks < 4; ++ks)
            a[ks] = *(const short8*)&center_bf[(size_t)(n0 + (l & 15)) * 128 + ks * 32 + ((l >> 4) << 3)];
        for (int ci = 0; ci < 16; ++ci) {
            int ct = w * 16 + ci;
            float4v acc = {};
            #pragma unroll
            for (int ks = 0; ks < 4; ++ks) {
                short8 b = *(const short8*)&BallQfrag[(((ks * 64 + ct) << 6) + l) * 8];
                acc = __builtin_amdgcn_mfma_f32_16x16x32_bf16(a[ks], b, acc, 0, 0, 0);
            }
            int r = ct >> 3;
            int ch = (ct & 7) * 16 + (l & 15);
            #pragma unroll
            for (int reg = 0; reg < 4; ++reg) {
                int rn = ((l >> 4) << 2) + reg;
                qlds[rn * QSTRIDE + r * 136 + ch] = f2bf(acc[reg]);
            }
        }
    }
    __syncthreads();

    // phase B: wave w handles nodes n0 + w*4 .. +4
    for (int q = 0; q < 4; ++q) {
        int tn = w * 4 + q;
        int n = n0 + tn;
        int ai[2], rv[2], rowv[2];
        #pragma unroll
        for (int t = 0; t < 2; ++t) {
            ai[t] = adj[n * DD + t * 16 + (l & 15)];
            rv[t] = rel[n * DD + t * 16 + (l & 15)];
            rowv[t] = ai[t] > 0 ? ai[t] - 1 : 0;
        }
        // scores via MFMA: X(edges x 128) @ Q^T  (reads qlds row tn only)
        float4v sc[2] = {};
        #pragma unroll
        for (int ks = 0; ks < 4; ++ks) {
            short8 qb = *(const short8*)&qlds[tn * QSTRIDE + (l & 7) * 136 + ks * 32 + ((l >> 4) << 3)];
            #pragma unroll
            for (int t = 0; t < 2; ++t) {
                short8 xa = *(const short8*)&center_bf[(size_t)rowv[t] * 128 + ks * 32 + ((l >> 4) << 3)];
                sc[t] = __builtin_amdgcn_mfma_f32_16x16x32_bf16(xa, qb, sc[t], 0, 0, 0);
            }
        }
        // select col rd per edge, mask, softmax
        float sel[2][4];
        int ai2[2][4];
        #pragma unroll
        for (int t = 0; t < 2; ++t)
            #pragma unroll
            for (int reg = 0; reg < 4; ++reg) {
                int e2l = ((l >> 4) & 3) * 4 + reg;
                int rd2 = __shfl(rv[t], (l & 48) | e2l, 64);
                ai2[t][reg] = __shfl(ai[t], (l & 48) | e2l, 64);
                float s = __shfl(sc[t][reg], (l & 48) | rd2, 64);
                if (ai2[t][reg] == 0) s = 0.f;
                if (rd2 == 0) s = -1e9f;
                sel[t][reg] = s;
            }
        float mx = sel[0][0];
        #pragma unroll
        for (int t = 0; t < 2; ++t)
            #pragma unroll
            for (int reg = 0; reg < 4; ++reg) mx = fmaxf(mx, sel[t][reg]);
        mx = fmaxf(mx, __shfl_xor(mx, 16, 64));
        mx = fmaxf(mx, __shfl_xor(mx, 32, 64));
        float at[2][4];
        float sm = 0.f;
        #pragma unroll
        for (int t = 0; t < 2; ++t)
            #pragma unroll
            for (int reg = 0; reg < 4; ++reg) {
                at[t][reg] = __expf(sel[t][reg] - mx);
                sm += at[t][reg];
            }
        sm += __shfl_xor(sm, 16, 64);
        sm += __shfl_xor(sm, 32, 64);
        float inv = 1.0f / sm;
        #pragma unroll
        for (int t = 0; t < 2; ++t)
            #pragma unroll
            for (int reg = 0; reg < 4; ++reg) {
                at[t][reg] *= inv;
                if (ai2[t][reg] == 0) at[t][reg] = 0.f;   // pad rows contribute 0
            }

        // bucket: predicated register accumulate (lane owns channels 2l, 2l+1)
        float bk0[8], bk1[8];
        #pragma unroll
        for (int r = 0; r < 8; ++r) { bk0[r] = 0.f; bk1[r] = 0.f; }
        #pragma unroll
        for (int t = 0; t < 2; ++t)
            #pragma unroll
            for (int g = 0; g < 4; ++g)
                #pragma unroll
                for (int reg = 0; reg < 4; ++reg) {
                    float ad = __shfl(at[t][reg], g << 4, 64);
                    int rowe = __shfl(rowv[t], g * 4 + reg, 64);
                    int rve  = __shfl(rv[t],  g * 4 + reg, 64);
                    unsigned xu = *(const unsigned*)&center_bf[(size_t)rowe * 128 + l * 2];
                    float x0 = bflo(xu), x1 = bfhi(xu);
                    #pragma unroll
                    for (int r = 0; r < 8; ++r) {
                        float am = (rve == r) ? ad : 0.f;
                        bk0[r] += am * x0;
                        bk1[r] += am * x1;
                    }
                }
        // qlds row tn is dead (this wave's own scores consumed it) -> overlay bucket row
        #pragma unroll
        for (int r = 0; r < 8; ++r) {
            unsigned pk = (unsigned)f2bf(bk0[r]) | ((unsigned)f2bf(bk1[r]) << 16);
            *(unsigned*)&qlds[tn * QSTRIDE + r * 128 + l * 2] = pk;
        }
    }
    __syncthreads();

    // phase C: agg16x128 = bucket(16x1024) @ RVF(1024x128), fused epilogue.
    // wave w does col-tiles w*2, w*2+1.
    #pragma unroll
    for (int ci = 0; ci < 2; ++ci) {
        int ct = w * 2 + ci;
        float4v acc = {};
        #pragma unroll 4
        for (int ks = 0; ks < 32; ++ks) {
            short8 a = *(const short8*)&qlds[(l & 15) * QSTRIDE + ks * 32 + ((l >> 4) << 3)];
            short8 b = *(const short8*)&RVFfrag[(((ks * 8 + ct) << 6) + l) * 8];
            acc = __builtin_amdgcn_mfma_f32_16x16x32_bf16(a, b, acc, 0, 0, 0);
        }
        int col = ct * 16 + (l & 15);
        float bb = fcb[col];
        #pragma unroll
        for (int reg = 0; reg < 4; ++reg) {
            int n = n0 + ((l >> 4) << 2) + reg;
            float v = acc[reg] + bb;
            v = v > 0.f ? v : 0.f;
            out[(size_t)n * 128 + col] = bf2f(center_bf[(size_t)n * 128 + col]) + v;
        }
    }
}

extern "C" void kernel_launch(void* const* d_in, const int* in_sizes, int n_in,
                              void* d_out, int out_size, void* d_ws, size_t ws_size,
                              hipStream_t stream) {
    const float* node_state = (const float*)d_in[0];
    const int*   adjacency  = (const int*)d_in[1];
    const int*   point_enc  = (const int*)d_in[2];
    const int*   relation   = (const int*)d_in[3];
    const float* pew        = (const float*)d_in[4];
    const float* relw       = (const float*)d_in[5];
    const float* qw         = (const float*)d_in[6];
    const float* kw         = (const float*)d_in[7];
    const float* vw         = (const float*)d_in[8];
    const float* fcw        = (const float*)d_in[9];
    const float* fcb        = (const float*)d_in[10];
    float* out = (float*)d_out;

    char* ws = (char*)d_ws;
    unsigned short* BallQfrag = (unsigned short*)ws;  ws += 128 * 1024 * 2;            // 256 KB
    unsigned short* RVFfrag   = (unsigned short*)ws;  ws += 1024 * 128 * 2;            // 256 KB
    unsigned short* center_bf = (unsigned short*)ws;  ws += (size_t)NNODE * 128 * 2;   // 4 MB
    unsigned short* pewfrag   = (unsigned short*)ws;  ws += 8 * 32768 * 2;             // 512 KB
    int* blockhist            = (int*)ws;             ws += 64 * 8 * 4;
    int* cnt                  = (int*)ws;             ws += 32;
    int* basep                = (int*)ws;             ws += 32;
    int* list                 = (int*)ws;             ws += NNODE * 4;                 // 64 KB

    k_setup<<<1152, 256, 0, stream>>>(pew, qw, kw, relw, vw, fcw, point_enc,
                                      pewfrag, BallQfrag, RVFfrag, blockhist);
    k_scatter<<<64, 256, 0, stream>>>(point_enc, blockhist, list, cnt, basep);
    k_center<<<dim3(192, 8), 256, 0, stream>>>(node_state, pewfrag, list, cnt, basep, center_bf);
    k_final<<<NNODE / 16, 256, 0, stream>>>(center_bf, BallQfrag, RVFfrag,
                                            adjacency, relation, fcb, out);
}

// Round 9
// 197.222 us; speedup vs baseline: 5.1178x; 1.1488x over previous
//
#include <hip/hip_runtime.h>

#define NNODE 16384
#define DD 32
#define INPC 256
#define UC 128
#define RC 8
#define EC 8

typedef __attribute__((ext_vector_type(8))) short short8;
typedef __attribute__((ext_vector_type(4))) float float4v;

__device__ __forceinline__ unsigned short f2bf(float f) {
    unsigned u = __builtin_bit_cast(unsigned, f);
    unsigned r = (u + 0x7FFFu + ((u >> 16) & 1u)) >> 16;   // RNE
    return (unsigned short)r;
}
__device__ __forceinline__ float bflo(unsigned u) { return __builtin_bit_cast(float, u << 16); }
__device__ __forceinline__ float bfhi(unsigned u) { return __builtin_bit_cast(float, u & 0xFFFF0000u); }
__device__ __forceinline__ float bf2f(unsigned short s) { return __builtin_bit_cast(float, (unsigned)s << 16); }

// B-fragment flat index for mfma_f32_16x16x32_bf16. nct = #16-col tiles.
__device__ __forceinline__ int bfrag_idx(int k, int col, int nct) {
    int ks = k >> 5, ct = col >> 4;
    int l = (((k >> 3) & 3) << 4) | (col & 15);
    return (((ks * nct + ct) << 6) + l) * 8 + (k & 7);
}

// ---------- setup: [0,1024) pew->frag | [1024,1088) prep | [1088,1152) hist ----------
__global__ void k_setup(const float* __restrict__ pew, const float* __restrict__ qw,
                        const float* __restrict__ kw, const float* __restrict__ relw,
                        const float* __restrict__ vw, const float* __restrict__ fcw,
                        const int* __restrict__ pe,
                        unsigned short* __restrict__ pewfrag,
                        unsigned short* __restrict__ BallQfrag, unsigned short* __restrict__ RVFfrag,
                        int* __restrict__ blockhist) {
    __shared__ float P_s[16 * 128];
    __shared__ int hh[8];
    int b = blockIdx.x;
    if (b < 1024) {                   // pew -> B-fragments (K=256, N=128 per entity)
        int id = b * 256 + threadIdx.x;
        int e = id >> 15, k = (id >> 7) & 255, col = id & 127;
        pewfrag[(e << 15) + bfrag_idx(k, col, 8)] = f2bf(pew[id]);
        return;
    }
    if (b < 1088) {                   // prep
        int pb = b - 1024;
        int r = pb & 7, i0 = (pb >> 3) * 16;
        int j = threadIdx.x & 127, h = threadIdx.x >> 7;
        {   // P rows i0..i0+16 = (q_w @ k_w^T)/128
            float acc[8] = {0,0,0,0,0,0,0,0};
            const float4* kr = (const float4*)(kw + j * UC);
            for (int lc = 0; lc < 32; ++lc) {
                float4 bb = kr[lc];
                #pragma unroll
                for (int ii = 0; ii < 8; ++ii) {
                    float4 a = *(const float4*)&qw[(i0 + h * 8 + ii) * UC + lc * 4];
                    acc[ii] += a.x * bb.x + a.y * bb.y + a.z * bb.z + a.w * bb.w;
                }
            }
            #pragma unroll
            for (int ii = 0; ii < 8; ++ii)
                P_s[(h * 8 + ii) * 128 + j] = acc[ii] * (1.0f / 128.0f);
        }
        __syncthreads();

        const float* R = relw + r * UC * UC;
        float accM[8] = {0,0,0,0,0,0,0,0};
        for (int mc = 0; mc < 32; ++mc) {
            float4 rv = *(const float4*)&R[j * UC + mc * 4];
            #pragma unroll
            for (int ii = 0; ii < 8; ++ii) {
                float4 p = *(const float4*)&P_s[(h * 8 + ii) * 128 + mc * 4];
                accM[ii] += p.x * rv.x + p.y * rv.y + p.z * rv.z + p.w * rv.w;
            }
        }
        #pragma unroll
        for (int ii = 0; ii < 8; ++ii)
            BallQfrag[bfrag_idx(i0 + h * 8 + ii, r * 128 + j, 64)] = f2bf(accM[ii]);

        // RV rows = rel_w[r] @ v_w (rows i0..+16)
        float accV[8] = {0,0,0,0,0,0,0,0};
        for (int m = 0; m < UC; ++m) {
            float v = vw[m * UC + j];
            #pragma unroll
            for (int ii = 0; ii < 8; ++ii)
                accV[ii] += R[(i0 + h * 8 + ii) * UC + m] * v;
        }
        __syncthreads();   // P_s dead, reuse for RV rows
        #pragma unroll
        for (int ii = 0; ii < 8; ++ii)
            P_s[(h * 8 + ii) * 128 + j] = accV[ii];
        __syncthreads();

        // RVF rows = RV rows @ fc_w; stored as B-frag with K=1024 (k=r*128+i), N=128
        float accF[8] = {0,0,0,0,0,0,0,0};
        for (int m = 0; m < UC; ++m) {
            float w = fcw[m * UC + j];
            #pragma unroll
            for (int ii = 0; ii < 8; ++ii)
                accF[ii] += P_s[(h * 8 + ii) * 128 + m] * w;
        }
        #pragma unroll
        for (int ii = 0; ii < 8; ++ii)
            RVFfrag[bfrag_idx(r * 128 + i0 + h * 8 + ii, j, 8)] = f2bf(accF[ii]);
        return;
    }
    {   // hist
        int hb = b - 1088;
        if (threadIdx.x < 8) hh[threadIdx.x] = 0;
        __syncthreads();
        atomicAdd(&hh[pe[hb * 256 + threadIdx.x]], 1);
        __syncthreads();
        if (threadIdx.x < 8) blockhist[hb * 8 + threadIdx.x] = hh[threadIdx.x];
    }
}

// ---------- scatter: wave-parallel scan + ballot rank (no global atomics) ----------
__global__ void k_scatter(const int* __restrict__ pe, const int* __restrict__ blockhist,
                          int* __restrict__ list, int* __restrict__ cnt, int* __restrict__ basep) {
    __shared__ int boff[8];
    __shared__ int totS[8], exS[8];
    __shared__ int wavecnt[4 * 8];
    int t = threadIdx.x, w = t >> 6, l = t & 63;
    if (w == 0) {
        // lane l owns source-block l; 6-step shfl prefix per entity
        #pragma unroll
        for (int e = 0; e < 8; ++e) {
            int h = blockhist[l * 8 + e];
            int pref = h;
            #pragma unroll
            for (int off = 1; off < 64; off <<= 1) {
                int v = __shfl_up(pref, off, 64);
                pref += (l >= off) ? v : 0;
            }
            if (l == (int)blockIdx.x) exS[e] = pref - h;   // excl. prefix of my block
            if (l == 63) totS[e] = pref;                   // entity total
        }
    }
    __syncthreads();
    if (t == 0) {
        int run = 0;
        #pragma unroll
        for (int e = 0; e < 8; ++e) {
            boff[e] = run + exS[e];
            if (blockIdx.x == 0) { basep[e] = run; cnt[e] = totS[e]; }
            run += totS[e];
        }
    }
    __syncthreads();
    int n = blockIdx.x * 256 + t;
    int e = pe[n];
    unsigned long long mymask = 0;
    #pragma unroll
    for (int r = 0; r < 8; ++r) {
        unsigned long long m = __ballot(e == r);
        if (e == r) mymask = m;
        if (l == r) wavecnt[w * 8 + r] = (int)__popcll(m);
    }
    __syncthreads();
    int off = 0;
    for (int w2 = 0; w2 < w; ++w2) off += wavecnt[w2 * 8 + e];
    unsigned long long ltmask = (1ull << l) - 1ull;
    int rank = (int)__popcll(mymask & ltmask);
    list[boff[e] + off + rank] = n;
}

// ---------- center (MFMA): reads fp32 ns directly, converts in-register ----------
__global__ __launch_bounds__(256, 4)
void k_center(const float* __restrict__ ns, const unsigned short* __restrict__ pewfrag,
              const int* __restrict__ list, const int* __restrict__ cnt,
              const int* __restrict__ base, unsigned short* __restrict__ center_bf) {
    int e = blockIdx.y;
    int c = cnt[e];
    int start = blockIdx.x * 16;
    if (start >= c) return;
    int w = threadIdx.x >> 6, l = threadIdx.x & 63;

    int rid = list[base[e] + min(start + (l & 15), c - 1)];

    float4v acc[2] = {};
    const unsigned short* pf = pewfrag + ((size_t)e << 15);
    #pragma unroll
    for (int ks = 0; ks < 8; ++ks) {
        const float* ap = &ns[(size_t)rid * 256 + ks * 32 + ((l >> 4) << 3)];
        float4 v0 = *(const float4*)ap;
        float4 v1 = *(const float4*)(ap + 4);
        short8 a;
        a[0] = f2bf(v0.x); a[1] = f2bf(v0.y); a[2] = f2bf(v0.z); a[3] = f2bf(v0.w);
        a[4] = f2bf(v1.x); a[5] = f2bf(v1.y); a[6] = f2bf(v1.z); a[7] = f2bf(v1.w);
        #pragma unroll
        for (int ci = 0; ci < 2; ++ci) {
            int ct = w * 2 + ci;
            short8 b = *(const short8*)&pf[(((ks * 8 + ct) << 6) + l) * 8];
            acc[ci] = __builtin_amdgcn_mfma_f32_16x16x32_bf16(a, b, acc[ci], 0, 0, 0);
        }
    }
    #pragma unroll
    for (int reg = 0; reg < 4; ++reg) {
        int row16 = start + ((l >> 4) << 2) + reg;
        if (row16 < c) {
            int gid = list[base[e] + row16];
            #pragma unroll
            for (int ci = 0; ci < 2; ++ci)
                center_bf[(size_t)gid * 128 + (w * 2 + ci) * 16 + (l & 15)] = f2bf(acc[ci][reg]);
        }
    }
}

// ---------- final: qr MFMA->LDS + scores MFMA + softmax + edata-staged bucket ->
//            LDS (overlaying dead qr rows) + bucket@RVF MFMA + epilogue ----------
#define QSTRIDE 1096   // elems/row; dword-stride 548 % 32 = 4 -> rows bank-spread
__global__ __launch_bounds__(256, 4)
void k_final(const unsigned short* __restrict__ center_bf,
             const unsigned short* __restrict__ BallQfrag,
             const unsigned short* __restrict__ RVFfrag,
             const int* __restrict__ adj, const int* __restrict__ rel,
             const float* __restrict__ fcb, float* __restrict__ out) {
    __shared__ unsigned short qlds[16 * QSTRIDE];   // ~35 KB
    __shared__ unsigned edata[4][32][2];            // per-wave edge staging, 1 KB
    int w = threadIdx.x >> 6, l = threadIdx.x & 63;
    int n0 = blockIdx.x * 16;

    // phase A: qr tile (16 nodes x 1024) into LDS; wave w computes cols w*256..+256
    {
        short8 a[4];
        #pragma unroll
        for (int ks = 0; ks < 4; ++ks)
            a[ks] = *(const short8*)&center_bf[(size_t)(n0 + (l & 15)) * 128 + ks * 32 + ((l >> 4) << 3)];
        for (int ci = 0; ci < 16; ++ci) {
            int ct = w * 16 + ci;
            float4v acc = {};
            #pragma unroll
            for (int ks = 0; ks < 4; ++ks) {
                short8 b = *(const short8*)&BallQfrag[(((ks * 64 + ct) << 6) + l) * 8];
                acc = __builtin_amdgcn_mfma_f32_16x16x32_bf16(a[ks], b, acc, 0, 0, 0);
            }
            int r = ct >> 3;
            int ch = (ct & 7) * 16 + (l & 15);
            #pragma unroll
            for (int reg = 0; reg < 4; ++reg) {
                int rn = ((l >> 4) << 2) + reg;
                qlds[rn * QSTRIDE + r * 136 + ch] = f2bf(acc[reg]);
            }
        }
    }
    __syncthreads();

    // phase B: wave w handles nodes n0 + w*4 .. +4
    for (int q = 0; q < 4; ++q) {
        int tn = w * 4 + q;
        int n = n0 + tn;
        int ai[2], rv[2], rowv[2];
        #pragma unroll
        for (int t = 0; t < 2; ++t) {
            ai[t] = adj[n * DD + t * 16 + (l & 15)];
            rv[t] = rel[n * DD + t * 16 + (l & 15)];
            rowv[t] = ai[t] > 0 ? ai[t] - 1 : 0;
        }
        // scores via MFMA: X(edges x 128) @ Q^T  (reads qlds row tn only)
        float4v sc[2] = {};
        #pragma unroll
        for (int ks = 0; ks < 4; ++ks) {
            short8 qb = *(const short8*)&qlds[tn * QSTRIDE + (l & 7) * 136 + ks * 32 + ((l >> 4) << 3)];
            #pragma unroll
            for (int t = 0; t < 2; ++t) {
                short8 xa = *(const short8*)&center_bf[(size_t)rowv[t] * 128 + ks * 32 + ((l >> 4) << 3)];
                sc[t] = __builtin_amdgcn_mfma_f32_16x16x32_bf16(xa, qb, sc[t], 0, 0, 0);
            }
        }
        // select col rd per edge, mask, softmax (all quad-uniform results)
        float sel[2][4];
        int ai2[2][4];
        #pragma unroll
        for (int t = 0; t < 2; ++t)
            #pragma unroll
            for (int reg = 0; reg < 4; ++reg) {
                int e2l = ((l >> 4) & 3) * 4 + reg;
                int rd2 = __shfl(rv[t], (l & 48) | e2l, 64);
                ai2[t][reg] = __shfl(ai[t], (l & 48) | e2l, 64);
                float s = __shfl(sc[t][reg], (l & 48) | rd2, 64);
                if (ai2[t][reg] == 0) s = 0.f;
                if (rd2 == 0) s = -1e9f;
                sel[t][reg] = s;
            }
        float mx = sel[0][0];
        #pragma unroll
        for (int t = 0; t < 2; ++t)
            #pragma unroll
            for (int reg = 0; reg < 4; ++reg) mx = fmaxf(mx, sel[t][reg]);
        mx = fmaxf(mx, __shfl_xor(mx, 16, 64));
        mx = fmaxf(mx, __shfl_xor(mx, 32, 64));
        float at[2][4];
        float sm = 0.f;
        #pragma unroll
        for (int t = 0; t < 2; ++t)
            #pragma unroll
            for (int reg = 0; reg < 4; ++reg) {
                at[t][reg] = __expf(sel[t][reg] - mx);
                sm += at[t][reg];
            }
        sm += __shfl_xor(sm, 16, 64);
        sm += __shfl_xor(sm, 32, 64);
        float inv = 1.0f / sm;
        #pragma unroll
        for (int t = 0; t < 2; ++t)
            #pragma unroll
            for (int reg = 0; reg < 4; ++reg) {
                at[t][reg] *= inv;
                if (ai2[t][reg] == 0) at[t][reg] = 0.f;   // pad rows contribute 0
            }

        // stage per-edge (at, rowv<<3|rv) once: lane q'*20+rg holds both the
        // quad-uniform at[t][rg] (quad q') and rowv/rv of edge t*16 + q'*4+rg.
        #pragma unroll
        for (int rg = 0; rg < 4; ++rg) {
            if (l == (l >> 4) * 20 + rg) {
                #pragma unroll
                for (int t = 0; t < 2; ++t) {
                    uint2 md;
                    md.x = __builtin_bit_cast(unsigned, at[t][rg]);
                    md.y = ((unsigned)rowv[t] << 3) | (unsigned)rv[t];
                    *(uint2*)&edata[w][t * 16 + (l & 15)][0] = md;
                }
            }
        }

        // bucket: uniform-address broadcast read per edge, independent gathers
        float bk0[8], bk1[8];
        #pragma unroll
        for (int r = 0; r < 8; ++r) { bk0[r] = 0.f; bk1[r] = 0.f; }
        #pragma unroll
        for (int d = 0; d < 32; ++d) {
            uint2 md = *(const uint2*)&edata[w][d][0];
            float ad = __builtin_bit_cast(float, md.x);
            int rowe = (int)(md.y >> 3);
            int rve = (int)(md.y & 7u);
            unsigned xu = *(const unsigned*)&center_bf[(size_t)rowe * 128 + l * 2];
            float x0 = bflo(xu), x1 = bfhi(xu);
            #pragma unroll
            for (int r = 0; r < 8; ++r) {
                float am = (rve == r) ? ad : 0.f;
                bk0[r] += am * x0;
                bk1[r] += am * x1;
            }
        }
        // qlds row tn is dead (this wave's own scores consumed it) -> overlay bucket row
        #pragma unroll
        for (int r = 0; r < 8; ++r) {
            unsigned pk = (unsigned)f2bf(bk0[r]) | ((unsigned)f2bf(bk1[r]) << 16);
            *(unsigned*)&qlds[tn * QSTRIDE + r * 128 + l * 2] = pk;
        }
    }
    __syncthreads();

    // phase C: agg16x128 = bucket(16x1024) @ RVF(1024x128), fused epilogue.
    #pragma unroll
    for (int ci = 0; ci < 2; ++ci) {
        int ct = w * 2 + ci;
        float4v acc = {};
        #pragma unroll 4
        for (int ks = 0; ks < 32; ++ks) {
            short8 a = *(const short8*)&qlds[(l & 15) * QSTRIDE + ks * 32 + ((l >> 4) << 3)];
            short8 b = *(const short8*)&RVFfrag[(((ks * 8 + ct) << 6) + l) * 8];
            acc = __builtin_amdgcn_mfma_f32_16x16x32_bf16(a, b, acc, 0, 0, 0);
        }
        int col = ct * 16 + (l & 15);
        float bb = fcb[col];
        #pragma unroll
        for (int reg = 0; reg < 4; ++reg) {
            int n = n0 + ((l >> 4) << 2) + reg;
            float v = acc[reg] + bb;
            v = v > 0.f ? v : 0.f;
            out[(size_t)n * 128 + col] = bf2f(center_bf[(size_t)n * 128 + col]) + v;
        }
    }
}

extern "C" void kernel_launch(void* const* d_in, const int* in_sizes, int n_in,
                              void* d_out, int out_size, void* d_ws, size_t ws_size,
                              hipStream_t stream) {
    const float* node_state = (const float*)d_in[0];
    const int*   adjacency  = (const int*)d_in[1];
    const int*   point_enc  = (const int*)d_in[2];
    const int*   relation   = (const int*)d_in[3];
    const float* pew        = (const float*)d_in[4];
    const float* relw       = (const float*)d_in[5];
    const float* qw         = (const float*)d_in[6];
    const float* kw         = (const float*)d_in[7];
    const float* vw         = (const float*)d_in[8];
    const float* fcw        = (const float*)d_in[9];
    const float* fcb        = (const float*)d_in[10];
    float* out = (float*)d_out;

    char* ws = (char*)d_ws;
    unsigned short* BallQfrag = (unsigned short*)ws;  ws += 128 * 1024 * 2;            // 256 KB
    unsigned short* RVFfrag   = (unsigned short*)ws;  ws += 1024 * 128 * 2;            // 256 KB
    unsigned short* center_bf = (unsigned short*)ws;  ws += (size_t)NNODE * 128 * 2;   // 4 MB
    unsigned short* pewfrag   = (unsigned short*)ws;  ws += 8 * 32768 * 2;             // 512 KB
    int* blockhist            = (int*)ws;             ws += 64 * 8 * 4;
    int* cnt                  = (int*)ws;             ws += 32;
    int* basep                = (int*)ws;             ws += 32;
    int* list                 = (int*)ws;             ws += NNODE * 4;                 // 64 KB

    k_setup<<<1152, 256, 0, stream>>>(pew, qw, kw, relw, vw, fcw, point_enc,
                                      pewfrag, BallQfrag, RVFfrag, blockhist);
    k_scatter<<<64, 256, 0, stream>>>(point_enc, blockhist, list, cnt, basep);
    k_center<<<dim3(192, 8), 256, 0, stream>>>(node_state, pewfrag, list, cnt, basep, center_bf);
    k_final<<<NNODE / 16, 256, 0, stream>>>(center_bf, BallQfrag, RVFfrag,
                                            adjacency, relation, fcb, out);
}

// Round 10
// 164.913 us; speedup vs baseline: 6.1205x; 1.1959x over previous
//
#include <hip/hip_runtime.h>

#define NNODE 16384
#define DD 32
#define INPC 256
#define UC 128
#define RC 8
#define EC 8

typedef __attribute__((ext_vector_type(8))) short short8;
typedef __attribute__((ext_vector_type(4))) float float4v;
typedef __attribute__((ext_vector_type(4))) unsigned uint4v;

__device__ __forceinline__ unsigned short f2bf(float f) {
    unsigned u = __builtin_bit_cast(unsigned, f);
    unsigned r = (u + 0x7FFFu + ((u >> 16) & 1u)) >> 16;   // RNE
    return (unsigned short)r;
}
__device__ __forceinline__ float bf2f(unsigned short s) { return __builtin_bit_cast(float, (unsigned)s << 16); }

// load 8 consecutive fp32 and convert to a bf16 MFMA fragment half
__device__ __forceinline__ short8 ld8bf(const float* p) {
    float4 v0 = *(const float4*)p;
    float4 v1 = *(const float4*)(p + 4);
    short8 a;
    a[0] = (short)f2bf(v0.x); a[1] = (short)f2bf(v0.y);
    a[2] = (short)f2bf(v0.z); a[3] = (short)f2bf(v0.w);
    a[4] = (short)f2bf(v1.x); a[5] = (short)f2bf(v1.y);
    a[6] = (short)f2bf(v1.z); a[7] = (short)f2bf(v1.w);
    return a;
}

// B-fragment flat index for mfma_f32_16x16x32_bf16. nct = #16-col tiles.
__device__ __forceinline__ int bfrag_idx(int k, int col, int nct) {
    int ks = k >> 5, ct = col >> 4;
    int l = (((k >> 3) & 3) << 4) | (col & 15);
    return (((ks * nct + ct) << 6) + l) * 8 + (k & 7);
}

// ---------- setup: [0,1024) pew->frag | [1024,1088) prep (MFMA) | [1088,1152) hist ----------
__global__ void k_setup(const float* __restrict__ pew, const float* __restrict__ qw,
                        const float* __restrict__ kw, const float* __restrict__ relw,
                        const float* __restrict__ vw, const float* __restrict__ fcw,
                        const int* __restrict__ pe,
                        unsigned short* __restrict__ pewfrag,
                        unsigned short* __restrict__ BallQfrag, unsigned short* __restrict__ RVFfrag,
                        int* __restrict__ blockhist) {
    __shared__ unsigned short stage_s[128 * 132];   // ~33.8 KB: vw then fcw (bf16)
    __shared__ unsigned short mat_s[16 * 136];      // ~4.35 KB: P then RV (bf16)
    __shared__ int hh[8];
    int b = blockIdx.x;
    if (b < 1024) {                   // pew -> B-fragments (K=256, N=128 per entity)
        int id = b * 256 + threadIdx.x;
        int e = id >> 15, k = (id >> 7) & 255, col = id & 127;
        pewfrag[(e << 15) + bfrag_idx(k, col, 8)] = f2bf(pew[id]);
        return;
    }
    if (b < 1088) {                   // prep: all four small GEMMs via MFMA
        int pb = b - 1024;
        int r = pb & 7, i0 = (pb >> 3) * 16;
        int w = threadIdx.x >> 6, l = threadIdx.x & 63;
        int mrow = l & 15, kgrp = (l >> 4) << 3;
        const float* R = relw + r * (UC * UC);

        // ---- phase P: P rows i0..i0+16 = qw[i0..] @ kw^T
        float4v accP[2] = {};
        #pragma unroll
        for (int ks = 0; ks < 4; ++ks) {
            short8 a = ld8bf(&qw[(i0 + mrow) * UC + ks * 32 + kgrp]);
            #pragma unroll
            for (int ci = 0; ci < 2; ++ci) {
                int ct = w * 2 + ci;
                short8 bf = ld8bf(&kw[(ct * 16 + mrow) * UC + ks * 32 + kgrp]);
                accP[ci] = __builtin_amdgcn_mfma_f32_16x16x32_bf16(a, bf, accP[ci], 0, 0, 0);
            }
        }
        #pragma unroll
        for (int ci = 0; ci < 2; ++ci)
            #pragma unroll
            for (int reg = 0; reg < 4; ++reg) {
                int row = ((l >> 4) << 2) + reg;
                int col = (w * 2 + ci) * 16 + mrow;
                mat_s[row * 136 + col] = f2bf(accP[ci][reg] * (1.0f / 128.0f));
            }
        // stage vw (bf16, stride 132)
        for (int it = 0; it < 16; ++it) {
            int idx = it * 256 + threadIdx.x;      // float4 index
            int row = idx >> 5, col = (idx & 31) * 4;
            float4 v = *(const float4*)&vw[row * UC + col];
            uint2 o;
            o.x = (unsigned)f2bf(v.x) | ((unsigned)f2bf(v.y) << 16);
            o.y = (unsigned)f2bf(v.z) | ((unsigned)f2bf(v.w) << 16);
            *(uint2*)&stage_s[row * 132 + col] = o;
        }
        __syncthreads();

        // ---- phase M: M = P @ R^T ; phase RV: RV = R @ vw (interleaved)
        float4v accM[2] = {}, accV[2] = {};
        #pragma unroll
        for (int ks = 0; ks < 4; ++ks) {
            short8 aM = *(const short8*)&mat_s[mrow * 136 + ks * 32 + kgrp];
            short8 aV = ld8bf(&R[(i0 + mrow) * UC + ks * 32 + kgrp]);
            #pragma unroll
            for (int ci = 0; ci < 2; ++ci) {
                int ct = w * 2 + ci;
                short8 bM = ld8bf(&R[(ct * 16 + mrow) * UC + ks * 32 + kgrp]);
                accM[ci] = __builtin_amdgcn_mfma_f32_16x16x32_bf16(aM, bM, accM[ci], 0, 0, 0);
                uint4v pv;
                #pragma unroll
                for (int jp = 0; jp < 4; ++jp) {
                    unsigned e0 = stage_s[(ks * 32 + kgrp + jp * 2) * 132 + ct * 16 + mrow];
                    unsigned e1 = stage_s[(ks * 32 + kgrp + jp * 2 + 1) * 132 + ct * 16 + mrow];
                    pv[jp] = e0 | (e1 << 16);
                }
                accV[ci] = __builtin_amdgcn_mfma_f32_16x16x32_bf16(
                    aV, __builtin_bit_cast(short8, pv), accV[ci], 0, 0, 0);
            }
        }
        #pragma unroll
        for (int ci = 0; ci < 2; ++ci)
            #pragma unroll
            for (int reg = 0; reg < 4; ++reg) {
                int i = i0 + ((l >> 4) << 2) + reg;
                int col = r * 128 + (w * 2 + ci) * 16 + mrow;
                BallQfrag[bfrag_idx(i, col, 64)] = f2bf(accM[ci][reg]);
            }
        __syncthreads();   // mat_s / stage_s reads done
        // store RV rows; stage fcw
        #pragma unroll
        for (int ci = 0; ci < 2; ++ci)
            #pragma unroll
            for (int reg = 0; reg < 4; ++reg)
                mat_s[(((l >> 4) << 2) + reg) * 136 + (w * 2 + ci) * 16 + mrow] = f2bf(accV[ci][reg]);
        for (int it = 0; it < 16; ++it) {
            int idx = it * 256 + threadIdx.x;
            int row = idx >> 5, col = (idx & 31) * 4;
            float4 v = *(const float4*)&fcw[row * UC + col];
            uint2 o;
            o.x = (unsigned)f2bf(v.x) | ((unsigned)f2bf(v.y) << 16);
            o.y = (unsigned)f2bf(v.z) | ((unsigned)f2bf(v.w) << 16);
            *(uint2*)&stage_s[row * 132 + col] = o;
        }
        __syncthreads();

        // ---- phase RVF: RVF = RV @ fcw
        float4v accF[2] = {};
        #pragma unroll
        for (int ks = 0; ks < 4; ++ks) {
            short8 aF = *(const short8*)&mat_s[mrow * 136 + ks * 32 + kgrp];
            #pragma unroll
            for (int ci = 0; ci < 2; ++ci) {
                int ct = w * 2 + ci;
                uint4v pv;
                #pragma unroll
                for (int jp = 0; jp < 4; ++jp) {
                    unsigned e0 = stage_s[(ks * 32 + kgrp + jp * 2) * 132 + ct * 16 + mrow];
                    unsigned e1 = stage_s[(ks * 32 + kgrp + jp * 2 + 1) * 132 + ct * 16 + mrow];
                    pv[jp] = e0 | (e1 << 16);
                }
                accF[ci] = __builtin_amdgcn_mfma_f32_16x16x32_bf16(
                    aF, __builtin_bit_cast(short8, pv), accF[ci], 0, 0, 0);
            }
        }
        #pragma unroll
        for (int ci = 0; ci < 2; ++ci)
            #pragma unroll
            for (int reg = 0; reg < 4; ++reg) {
                int i = i0 + ((l >> 4) << 2) + reg;
                int col = (w * 2 + ci) * 16 + mrow;
                RVFfrag[bfrag_idx(r * 128 + i, col, 8)] = f2bf(accF[ci][reg]);
            }
        return;
    }
    {   // hist
        int hb = b - 1088;
        if (threadIdx.x < 8) hh[threadIdx.x] = 0;
        __syncthreads();
        atomicAdd(&hh[pe[hb * 256 + threadIdx.x]], 1);
        __syncthreads();
        if (threadIdx.x < 8) blockhist[hb * 8 + threadIdx.x] = hh[threadIdx.x];
    }
}

// ---------- scatter: wave-parallel scan + ballot rank (no global atomics) ----------
__global__ void k_scatter(const int* __restrict__ pe, const int* __restrict__ blockhist,
                          int* __restrict__ list, int* __restrict__ cnt, int* __restrict__ basep) {
    __shared__ int boff[8];
    __shared__ int totS[8], exS[8];
    __shared__ int wavecnt[4 * 8];
    int t = threadIdx.x, w = t >> 6, l = t & 63;
    if (w == 0) {
        #pragma unroll
        for (int e = 0; e < 8; ++e) {
            int h = blockhist[l * 8 + e];
            int pref = h;
            #pragma unroll
            for (int off = 1; off < 64; off <<= 1) {
                int v = __shfl_up(pref, off, 64);
                pref += (l >= off) ? v : 0;
            }
            if (l == (int)blockIdx.x) exS[e] = pref - h;
            if (l == 63) totS[e] = pref;
        }
    }
    __syncthreads();
    if (t == 0) {
        int run = 0;
        #pragma unroll
        for (int e = 0; e < 8; ++e) {
            boff[e] = run + exS[e];
            if (blockIdx.x == 0) { basep[e] = run; cnt[e] = totS[e]; }
            run += totS[e];
        }
    }
    __syncthreads();
    int n = blockIdx.x * 256 + t;
    int e = pe[n];
    unsigned long long mymask = 0;
    #pragma unroll
    for (int r = 0; r < 8; ++r) {
        unsigned long long m = __ballot(e == r);
        if (e == r) mymask = m;
        if (l == r) wavecnt[w * 8 + r] = (int)__popcll(m);
    }
    __syncthreads();
    int off = 0;
    for (int w2 = 0; w2 < w; ++w2) off += wavecnt[w2 * 8 + e];
    unsigned long long ltmask = (1ull << l) - 1ull;
    int rank = (int)__popcll(mymask & ltmask);
    list[boff[e] + off + rank] = n;
}

// ---------- center (MFMA): reads fp32 ns directly, converts in-register ----------
__global__ __launch_bounds__(256, 4)
void k_center(const float* __restrict__ ns, const unsigned short* __restrict__ pewfrag,
              const int* __restrict__ list, const int* __restrict__ cnt,
              const int* __restrict__ base, unsigned short* __restrict__ center_bf) {
    int e = blockIdx.y;
    int c = cnt[e];
    int start = blockIdx.x * 16;
    if (start >= c) return;
    int w = threadIdx.x >> 6, l = threadIdx.x & 63;

    int rid = list[base[e] + min(start + (l & 15), c - 1)];

    float4v acc[2] = {};
    const unsigned short* pf = pewfrag + ((size_t)e << 15);
    #pragma unroll
    for (int ks = 0; ks < 8; ++ks) {
        short8 a = ld8bf(&ns[(size_t)rid * 256 + ks * 32 + ((l >> 4) << 3)]);
        #pragma unroll
        for (int ci = 0; ci < 2; ++ci) {
            int ct = w * 2 + ci;
            short8 b = *(const short8*)&pf[(((ks * 8 + ct) << 6) + l) * 8];
            acc[ci] = __builtin_amdgcn_mfma_f32_16x16x32_bf16(a, b, acc[ci], 0, 0, 0);
        }
    }
    #pragma unroll
    for (int reg = 0; reg < 4; ++reg) {
        int row16 = start + ((l >> 4) << 2) + reg;
        if (row16 < c) {
            int gid = list[base[e] + row16];
            #pragma unroll
            for (int ci = 0; ci < 2; ++ci)
                center_bf[(size_t)gid * 128 + (w * 2 + ci) * 16 + (l & 15)] = f2bf(acc[ci][reg]);
        }
    }
}

// ---------- final: qr MFMA->LDS + scores MFMA + softmax + bucket MFMA ->
//            LDS (overlaying dead qr rows) + bucket@RVF MFMA + epilogue ----------
#define QSTRIDE 1096
__global__ __launch_bounds__(256, 4)
void k_final(const unsigned short* __restrict__ center_bf,
             const unsigned short* __restrict__ BallQfrag,
             const unsigned short* __restrict__ RVFfrag,
             const int* __restrict__ adj, const int* __restrict__ rel,
             const float* __restrict__ fcb, float* __restrict__ out) {
    __shared__ unsigned short qlds[16 * QSTRIDE];   // ~35 KB
    __shared__ uint2 edata[4][32];                  // per-wave edge staging, 1 KB
    int w = threadIdx.x >> 6, l = threadIdx.x & 63;
    int n0 = blockIdx.x * 16;

    // phase A: qr tile (16 nodes x 1024) into LDS; wave w computes cols w*256..+256
    {
        short8 a[4];
        #pragma unroll
        for (int ks = 0; ks < 4; ++ks)
            a[ks] = *(const short8*)&center_bf[(size_t)(n0 + (l & 15)) * 128 + ks * 32 + ((l >> 4) << 3)];
        for (int ci = 0; ci < 16; ++ci) {
            int ct = w * 16 + ci;
            float4v acc = {};
            #pragma unroll
            for (int ks = 0; ks < 4; ++ks) {
                short8 b = *(const short8*)&BallQfrag[(((ks * 64 + ct) << 6) + l) * 8];
                acc = __builtin_amdgcn_mfma_f32_16x16x32_bf16(a[ks], b, acc, 0, 0, 0);
            }
            int r = ct >> 3;
            int ch = (ct & 7) * 16 + (l & 15);
            #pragma unroll
            for (int reg = 0; reg < 4; ++reg) {
                int rn = ((l >> 4) << 2) + reg;
                qlds[rn * QSTRIDE + r * 136 + ch] = f2bf(acc[reg]);
            }
        }
    }
    __syncthreads();

    // phase B: wave w handles nodes n0 + w*4 .. +4
    for (int q = 0; q < 4; ++q) {
        int tn = w * 4 + q;
        int n = n0 + tn;
        int ai[2], rv[2], rowv[2];
        #pragma unroll
        for (int t = 0; t < 2; ++t) {
            ai[t] = adj[n * DD + t * 16 + (l & 15)];
            rv[t] = rel[n * DD + t * 16 + (l & 15)];
            rowv[t] = ai[t] > 0 ? ai[t] - 1 : 0;
        }
        // scores via MFMA: X(edges x 128) @ Q^T  (reads qlds row tn only)
        float4v sc[2] = {};
        #pragma unroll
        for (int ks = 0; ks < 4; ++ks) {
            short8 qb = *(const short8*)&qlds[tn * QSTRIDE + (l & 7) * 136 + ks * 32 + ((l >> 4) << 3)];
            #pragma unroll
            for (int t = 0; t < 2; ++t) {
                short8 xa = *(const short8*)&center_bf[(size_t)rowv[t] * 128 + ks * 32 + ((l >> 4) << 3)];
                sc[t] = __builtin_amdgcn_mfma_f32_16x16x32_bf16(xa, qb, sc[t], 0, 0, 0);
            }
        }
        // select col rd per edge, mask, softmax (quad-uniform results)
        float sel[2][4];
        int ai2[2][4];
        #pragma unroll
        for (int t = 0; t < 2; ++t)
            #pragma unroll
            for (int reg = 0; reg < 4; ++reg) {
                int e2l = ((l >> 4) & 3) * 4 + reg;
                int rd2 = __shfl(rv[t], (l & 48) | e2l, 64);
                ai2[t][reg] = __shfl(ai[t], (l & 48) | e2l, 64);
                float s = __shfl(sc[t][reg], (l & 48) | rd2, 64);
                if (ai2[t][reg] == 0) s = 0.f;
                if (rd2 == 0) s = -1e9f;
                sel[t][reg] = s;
            }
        float mx = sel[0][0];
        #pragma unroll
        for (int t = 0; t < 2; ++t)
            #pragma unroll
            for (int reg = 0; reg < 4; ++reg) mx = fmaxf(mx, sel[t][reg]);
        mx = fmaxf(mx, __shfl_xor(mx, 16, 64));
        mx = fmaxf(mx, __shfl_xor(mx, 32, 64));
        float at[2][4];
        float sm = 0.f;
        #pragma unroll
        for (int t = 0; t < 2; ++t)
            #pragma unroll
            for (int reg = 0; reg < 4; ++reg) {
                at[t][reg] = __expf(sel[t][reg] - mx);
                sm += at[t][reg];
            }
        sm += __shfl_xor(sm, 16, 64);
        sm += __shfl_xor(sm, 32, 64);
        float inv = 1.0f / sm;
        #pragma unroll
        for (int t = 0; t < 2; ++t)
            #pragma unroll
            for (int reg = 0; reg < 4; ++reg) {
                at[t][reg] *= inv;
                if (ai2[t][reg] == 0) at[t][reg] = 0.f;   // pad rows contribute 0
            }

        // stage per-edge (rowv, bf16(at) | rv<<16)
        #pragma unroll
        for (int rg = 0; rg < 4; ++rg) {
            if (l == (l >> 4) * 20 + rg) {
                #pragma unroll
                for (int t = 0; t < 2; ++t) {
                    uint2 md;
                    md.x = (unsigned)rowv[t];
                    md.y = (unsigned)f2bf(at[t][rg]) | ((unsigned)rv[t] << 16);
                    edata[w][t * 16 + (l & 15)] = md;
                }
            }
        }

        // bucket via MFMA: C(16rel x 128ch) = P(at selection) @ Xg(32 x 128)
        unsigned aw[4];
        int rows[8];
        #pragma unroll
        for (int jp = 0; jp < 4; ++jp) {
            uint2 m0 = edata[w][((l >> 4) << 3) + jp * 2];
            uint2 m1 = edata[w][((l >> 4) << 3) + jp * 2 + 1];
            unsigned s0 = ((m0.y >> 16) == (unsigned)(l & 15)) ? (m0.y & 0xFFFFu) : 0u;
            unsigned s1 = ((m1.y >> 16) == (unsigned)(l & 15)) ? (m1.y & 0xFFFFu) : 0u;
            aw[jp] = s0 | (s1 << 16);
            rows[jp * 2] = (int)m0.x;
            rows[jp * 2 + 1] = (int)m1.x;
        }
        uint4v av = {aw[0], aw[1], aw[2], aw[3]};
        short8 afrag = __builtin_bit_cast(short8, av);
        const unsigned short* xb0 = center_bf + (size_t)rows[0] * 128 + (l & 15);
        const unsigned short* xb1 = center_bf + (size_t)rows[1] * 128 + (l & 15);
        const unsigned short* xb2 = center_bf + (size_t)rows[2] * 128 + (l & 15);
        const unsigned short* xb3 = center_bf + (size_t)rows[3] * 128 + (l & 15);
        const unsigned short* xb4 = center_bf + (size_t)rows[4] * 128 + (l & 15);
        const unsigned short* xb5 = center_bf + (size_t)rows[5] * 128 + (l & 15);
        const unsigned short* xb6 = center_bf + (size_t)rows[6] * 128 + (l & 15);
        const unsigned short* xb7 = center_bf + (size_t)rows[7] * 128 + (l & 15);
        #pragma unroll
        for (int ct = 0; ct < 8; ++ct) {
            unsigned p0 = xb0[ct * 16], p1 = xb1[ct * 16], p2 = xb2[ct * 16], p3 = xb3[ct * 16];
            unsigned p4 = xb4[ct * 16], p5 = xb5[ct * 16], p6 = xb6[ct * 16], p7 = xb7[ct * 16];
            uint4v bv = {p0 | (p1 << 16), p2 | (p3 << 16), p4 | (p5 << 16), p6 | (p7 << 16)};
            float4v zc = {};
            float4v acc = __builtin_amdgcn_mfma_f32_16x16x32_bf16(
                afrag, __builtin_bit_cast(short8, bv), zc, 0, 0, 0);
            if (l < 32) {     // C rows 0..7 = relations; rows 8..15 are zero
                int rbase = (l >> 4) << 2;
                #pragma unroll
                for (int reg = 0; reg < 4; ++reg)
                    qlds[tn * QSTRIDE + (rbase + reg) * 136 + ct * 16 + (l & 15)] = f2bf(acc[reg]);
            }
        }
    }
    __syncthreads();

    // phase C: agg16x128 = bucket(16x1024, r-stride 136) @ RVF(1024x128), fused epilogue
    #pragma unroll
    for (int ci = 0; ci < 2; ++ci) {
        int ct = w * 2 + ci;
        float4v acc = {};
        #pragma unroll 4
        for (int ks = 0; ks < 32; ++ks) {
            short8 a = *(const short8*)&qlds[(l & 15) * QSTRIDE + (ks >> 2) * 136
                                             + (ks & 3) * 32 + ((l >> 4) << 3)];
            short8 b = *(const short8*)&RVFfrag[(((ks * 8 + ct) << 6) + l) * 8];
            acc = __builtin_amdgcn_mfma_f32_16x16x32_bf16(a, b, acc, 0, 0, 0);
        }
        int col = ct * 16 + (l & 15);
        float bb = fcb[col];
        #pragma unroll
        for (int reg = 0; reg < 4; ++reg) {
            int n = n0 + ((l >> 4) << 2) + reg;
            float v = acc[reg] + bb;
            v = v > 0.f ? v : 0.f;
            out[(size_t)n * 128 + col] = bf2f(center_bf[(size_t)n * 128 + col]) + v;
        }
    }
}

extern "C" void kernel_launch(void* const* d_in, const int* in_sizes, int n_in,
                              void* d_out, int out_size, void* d_ws, size_t ws_size,
                              hipStream_t stream) {
    const float* node_state = (const float*)d_in[0];
    const int*   adjacency  = (const int*)d_in[1];
    const int*   point_enc  = (const int*)d_in[2];
    const int*   relation   = (const int*)d_in[3];
    const float* pew        = (const float*)d_in[4];
    const float* relw       = (const float*)d_in[5];
    const float* qw         = (const float*)d_in[6];
    const float* kw         = (const float*)d_in[7];
    const float* vw         = (const float*)d_in[8];
    const float* fcw        = (const float*)d_in[9];
    const float* fcb        = (const float*)d_in[10];
    float* out = (float*)d_out;

    char* ws = (char*)d_ws;
    unsigned short* BallQfrag = (unsigned short*)ws;  ws += 128 * 1024 * 2;            // 256 KB
    unsigned short* RVFfrag   = (unsigned short*)ws;  ws += 1024 * 128 * 2;            // 256 KB
    unsigned short* center_bf = (unsigned short*)ws;  ws += (size_t)NNODE * 128 * 2;   // 4 MB
    unsigned short* pewfrag   = (unsigned short*)ws;  ws += 8 * 32768 * 2;             // 512 KB
    int* blockhist            = (int*)ws;             ws += 64 * 8 * 4;
    int* cnt                  = (int*)ws;             ws += 32;
    int* basep                = (int*)ws;             ws += 32;
    int* list                 = (int*)ws;             ws += NNODE * 4;                 // 64 KB

    k_setup<<<1152, 256, 0, stream>>>(pew, qw, kw, relw, vw, fcw, point_enc,
                                      pewfrag, BallQfrag, RVFfrag, blockhist);
    k_scatter<<<64, 256, 0, stream>>>(point_enc, blockhist, list, cnt, basep);
    k_center<<<dim3(192, 8), 256, 0, stream>>>(node_state, pewfrag, list, cnt, basep, center_bf);
    k_final<<<NNODE / 16, 256, 0, stream>>>(center_bf, BallQfrag, RVFfrag,
                                            adjacency, relation, fcb, out);
}